// Round 5
// baseline (511.597 us; speedup 1.0000x reference)
//
#include <hip/hip_runtime.h>
#include <hip/hip_bf16.h>

// Problem constants
#define Bsz 4
#define Tsz 2048
#define Dsz 1024
#define Ssz 16
#define Esz 2048
#define Mrows (Bsz*Tsz)        // 8192

typedef __attribute__((ext_vector_type(8))) short short8;
typedef __attribute__((ext_vector_type(4))) float floatx4;
typedef __attribute__((ext_vector_type(4))) unsigned short ushort4v;

__device__ __forceinline__ void async_ld16(const void* g, void* l) {
    __builtin_amdgcn_global_load_lds(
        (const __attribute__((address_space(1))) void*)g,
        (__attribute__((address_space(3))) void*)l,
        16, 0, 0);
}

__device__ __forceinline__ float sigmoidf_(float v) { return 1.f / (1.f + expf(-v)); }
__device__ __forceinline__ float bf2f(unsigned short u) {
    union { unsigned u32; float f; } c; c.u32 = (unsigned)u << 16; return c.f;
}
__device__ __forceinline__ unsigned short f2bf(float f) {
    __hip_bfloat16 h = __float2bfloat16(f);
    return *(unsigned short*)&h;
}

// s_waitcnt immediates (gfx9): vm[3:0]|exp[6:4]|lgkm[11:8]|vm[15:14]
#define WAIT_VM(N)   (0xF70 | (N))

// ---------------------------------------------------------------------------
// merged conversions to bf16: x, in_w, dt_w, out_w (f32 -> bf16, no scaling;
// R5 dropped the fp8 path: five fp8 kernel variants were all pinned at
// ~600 TF; bf16-m97 is the refcheck'd 912 TF structure on this chip).
// Each thread: one float4 -> 4 bf16 (8B store).
// ---------------------------------------------------------------------------
#define CV_S0 2097152   // x:     8388608 f32 / 4
#define CV_S1 3145728   // in_w: +4194304 / 4
#define CV_S2 4194304   // dt_w: +4194304 / 4
#define CV_S3 4718592   // out_w:+2097152 / 4
__global__ void cvt_all(const float4* __restrict__ x,  const float4* __restrict__ iw,
                        const float4* __restrict__ dw, const float4* __restrict__ ow,
                        ushort4v* __restrict__ xb, ushort4v* __restrict__ iwb,
                        ushort4v* __restrict__ dwb, ushort4v* __restrict__ owb) {
    int i = blockIdx.x * blockDim.x + threadIdx.x;
    const int stride = gridDim.x * blockDim.x;
    for (; i < CV_S3; i += stride) {
        float4 v; ushort4v* dst; int j;
        if (i < CV_S0)      { j = i;         v = x[j];  dst = xb; }
        else if (i < CV_S1) { j = i - CV_S0; v = iw[j]; dst = iwb; }
        else if (i < CV_S2) { j = i - CV_S1; v = dw[j]; dst = dwb; }
        else                { j = i - CV_S2; v = ow[j]; dst = owb; }
        ushort4v o;
        o[0] = f2bf(v.x); o[1] = f2bf(v.y); o[2] = f2bf(v.z); o[3] = f2bf(v.w);
        dst[j] = o;
    }
}

// ---------------------------------------------------------------------------
// m97-faithful bf16 GEMM: C[M,N] = A[M,K] @ Bw[N,K]^T (+bias).
// 128x128 tile, BK=32 bf16 (64B), 4 waves 2x2, per-wave 64x64 via 4x4
// mfma_f32_16x16x32_bf16.  LDS linear [128][32] bf16 per stage (no swizzle:
// frag reads are 2-way bank-aliased = free, m136).  Fragment = ONE
// ds_read_b128 (16B/lane), no shufflevector, no scale operands.
// 2-stage LDS (32 KB total -> 3 blk/CU at <=168 VGPR), one vmcnt(0) +
// barrier per K-tile, prefetch after barrier (R2-proven race-free skeleton).
// MODE: 0 bf16 store+bias, 1 softplus rowsum, 2 fp32 resid+ys*acc+bias.
// ---------------------------------------------------------------------------
template<int MODE>
__launch_bounds__(256, 3)
__global__ void gemm_bf(const unsigned char* __restrict__ A,   // bf16 bytes
                        const unsigned char* __restrict__ Bw,  // bf16 bytes
                        const float* __restrict__ bias,
                        int M, int N, int K,                   // K in elements
                        __hip_bfloat16* __restrict__ outb,
                        float* __restrict__ rowsum,
                        const float* __restrict__ resid,
                        const float* __restrict__ ysv,
                        float* __restrict__ outf) {
    __shared__ __align__(16) unsigned char sA[2 * 8192];   // 128 rows x 64B
    __shared__ __align__(16) unsigned char sB[2 * 8192];

    const int tid  = threadIdx.x;
    const int wave = tid >> 6, lane = tid & 63;
    const int wm = wave >> 1, wn = wave & 1;
    const int q = lane >> 4, lr = lane & 15;

    // XCD-aware remap: each XCD owns a contiguous M-stripe (gy % 8 == 0).
    const int gx = gridDim.x, gy = gridDim.y;
    const int flat = blockIdx.y * gx + blockIdx.x;
    const int stripe = gy >> 3;
    const int xcd = flat & 7, local = flat >> 3;
    const int mt = xcd * stripe + (local % stripe);
    const int nt = local / stripe;
    const int m0 = mt * 128, n0 = nt * 128;

    floatx4 acc[4][4];
#pragma unroll
    for (int i = 0; i < 4; ++i)
#pragma unroll
        for (int j = 0; j < 4; ++j) acc[i][j] = (floatx4){0.f, 0.f, 0.f, 0.f};

    // staging (linear): element idx = i*256+tid -> row = idx>>2, chunk = idx&3
    // (4 x 16B chunks per 64B row).  A-tile 8KB: i = 0,1.  Same for B.
    const size_t rbytes = (size_t)K * 2;   // row stride in bytes
    const unsigned char* pa[2];
    const unsigned char* pb[2];
#pragma unroll
    for (int i = 0; i < 2; ++i) {
        const int idx = i * 256 + tid, row = idx >> 2, ch = idx & 3;
        pa[i] = A  + (size_t)(m0 + row) * rbytes + ch * 16;
        pb[i] = Bw + (size_t)(n0 + row) * rbytes + ch * 16;
    }

    // fragment offsets: frag f at row wm*64 + f*16 + lr, byte col q*16
    const int oA = (wm * 64 + lr) * 64 + q * 16;   // + f*1024
    const int oB = (wn * 64 + lr) * 64 + q * 16;   // + g*1024

#define BF_ISSUE(ST) do {                                                      \
        _Pragma("unroll")                                                      \
        for (int i = 0; i < 2; ++i) {                                          \
            async_ld16(pa[i], &sA[(ST) * 8192 + (i * 256 + wave * 64) * 16]);  \
            pa[i] += 64;                                                       \
        }                                                                      \
        _Pragma("unroll")                                                      \
        for (int i = 0; i < 2; ++i) {                                          \
            async_ld16(pb[i], &sB[(ST) * 8192 + (i * 256 + wave * 64) * 16]);  \
            pb[i] += 64;                                                       \
        }                                                                      \
    } while (0)

    const int ntile = K >> 5;      // K-tiles of 32 elements
    BF_ISSUE(0);                   // tile 0 -> stage 0
    for (int kt = 0; kt < ntile; ++kt) {
        const int st = kt & 1;
        const int base = st * 8192;
        __builtin_amdgcn_s_waitcnt(WAIT_VM(0));   // own tile-kt loads landed
        __syncthreads();                          // all waves: landed + prev reads done
        BF_ISSUE(st ^ 1);          // prefetch tile kt+1 (tail: garbage, never used)

        short8 a8[4], b8[4];
#pragma unroll
        for (int i = 0; i < 4; ++i)
            a8[i] = *(const short8*)&sA[base + oA + i * 1024];
#pragma unroll
        for (int j = 0; j < 4; ++j)
            b8[j] = *(const short8*)&sB[base + oB + j * 1024];
#pragma unroll
        for (int i = 0; i < 4; ++i)
#pragma unroll
            for (int j = 0; j < 4; ++j)
                acc[i][j] = __builtin_amdgcn_mfma_f32_16x16x32_bf16(
                    a8[i], b8[j], acc[i][j], 0, 0, 0);
    }
#undef BF_ISSUE
    __builtin_amdgcn_s_waitcnt(WAIT_VM(0));       // drain garbage tail tile

    // epilogue: C/D layout col = lane&15, row = (lane>>4)*4 + reg
    if (MODE == 0) {
#pragma unroll
        for (int i = 0; i < 4; ++i) {
            const int row = m0 + wm * 64 + i * 16 + q * 4;
#pragma unroll
            for (int j = 0; j < 4; ++j) {
                const int col = n0 + wn * 64 + j * 16 + lr;
                const float bc = bias[col];
#pragma unroll
                for (int r = 0; r < 4; ++r)
                    outb[(size_t)(row + r) * N + col] = __float2bfloat16(acc[i][j][r] + bc);
            }
        }
    } else if (MODE == 1) {
#pragma unroll
        for (int i = 0; i < 4; ++i) {
            float rs[4] = {0.f, 0.f, 0.f, 0.f};
#pragma unroll
            for (int j = 0; j < 4; ++j) {
                const int col = n0 + wn * 64 + j * 16 + lr;
                const float bc = bias[col];
#pragma unroll
                for (int r = 0; r < 4; ++r) {
                    float v = acc[i][j][r] + bc;
                    float sp = (v > 20.f) ? v : log1pf(expf(v));
                    rs[r] += sp;
                }
            }
#pragma unroll
            for (int r = 0; r < 4; ++r) {
                float v = rs[r];
                v += __shfl_xor(v, 1); v += __shfl_xor(v, 2);
                v += __shfl_xor(v, 4); v += __shfl_xor(v, 8);
                if (lr == 0)
                    atomicAdd(&rowsum[m0 + wm * 64 + i * 16 + q * 4 + r], v);
            }
        }
    } else {
        // out = resid + ys[row]*acc + bias  (y@W^T == diag(ys)*(S@W^T))
#pragma unroll
        for (int i = 0; i < 4; ++i) {
            const int row = m0 + wm * 64 + i * 16 + q * 4;
#pragma unroll
            for (int j = 0; j < 4; ++j) {
                const int col = n0 + wn * 64 + j * 16 + lr;
                const float bc = bias[col];
#pragma unroll
                for (int r = 0; r < 4; ++r) {
                    const size_t idx = (size_t)(row + r) * N + col;
                    outf[idx] = resid[idx] + ysv[row + r] * acc[i][j][r] + bc;
                }
            }
        }
    }
}

// ---------------------------------------------------------------------------
// fused elementwise pass over xp: depthwise conv(k=3)+bias+SiLU on main half
// -> xc (bf16, GEMM2 A + bcd input); SiLU on gate half -> S (bf16, GEMM3 A).
// ---------------------------------------------------------------------------
__global__ void conv_gate_k(const __hip_bfloat16* __restrict__ xp,
                            const float* __restrict__ cw,
                            const float* __restrict__ cb,
                            __hip_bfloat16* __restrict__ xc,
                            __hip_bfloat16* __restrict__ sgate) {
    const int idx8 = blockIdx.x * blockDim.x + threadIdx.x;
    const int e = (idx8 & (Esz / 8 - 1)) * 8;
    const int r = idx8 >> 8;
    const int t = r & (Tsz - 1);
    const unsigned short* row0 = (const unsigned short*)(xp + (size_t)r * (2 * Esz) + e);
    short8 vm1 = (t > 0)       ? *(const short8*)(row0 - 2 * Esz) : (short8){0,0,0,0,0,0,0,0};
    short8 v00 = *(const short8*)row0;
    short8 vp1 = (t < Tsz - 1) ? *(const short8*)(row0 + 2 * Esz) : (short8){0,0,0,0,0,0,0,0};
    short8 o;
#pragma unroll
    for (int k = 0; k < 8; ++k) {
        const int ek = e + k;
        float v = bf2f((unsigned short)vm1[k]) * cw[ek * 3 + 0]
                + bf2f((unsigned short)v00[k]) * cw[ek * 3 + 1]
                + bf2f((unsigned short)vp1[k]) * cw[ek * 3 + 2] + cb[ek];
        float sil = v * sigmoidf_(v);
        o[k] = (short)f2bf(sil);
    }
    *(short8*)(xc + (size_t)idx8 * 8) = o;

    // gate half -> S = silu(gate), bf16
    short8 g = *(const short8*)(row0 + Esz);
    short8 os;
#pragma unroll
    for (int k = 0; k < 8; ++k) {
        const float gv = bf2f((unsigned short)g[k]);
        os[k] = (short)f2bf(gv * sigmoidf_(gv));
    }
    *(short8*)(sgate + (size_t)idx8 * 8) = os;
}

// ---------------------------------------------------------------------------
// pack B_w/C_w/D_w (each [16,2048] fp32) into Wb [48,2048] bf16
// ---------------------------------------------------------------------------
__global__ void pack_bcd(const float* __restrict__ Bw, const float* __restrict__ Cw,
                         const float* __restrict__ Dw, __hip_bfloat16* __restrict__ Wb) {
    const int idx = blockIdx.x * blockDim.x + threadIdx.x;
    if (idx >= 48 * Esz) return;
    const int row = idx >> 11, col = idx & (Esz - 1);
    float v;
    if (row < 16)      v = Bw[row * Esz + col];
    else if (row < 32) v = Cw[(row - 16) * Esz + col];
    else               v = Dw[(row - 32) * Esz + col];
    Wb[idx] = __float2bfloat16(v);
}

// ---------------------------------------------------------------------------
// B/C/D projections via MFMA skinny GEMM: xc[M,E] @ Wb[48,E]^T.
// ---------------------------------------------------------------------------
__launch_bounds__(256)
__global__ void bcd_mfma(const __hip_bfloat16* __restrict__ xc,
                         const __hip_bfloat16* __restrict__ Wb,
                         const float* __restrict__ Bb, const float* __restrict__ Cb,
                         const float* __restrict__ Db,
                         float* __restrict__ u, float* __restrict__ Ct) {
    __shared__ __align__(16) __hip_bfloat16 sA[64 * 32];
    __shared__ __align__(16) __hip_bfloat16 sW[48 * 32];
    const int tid = threadIdx.x;
    const int wave = tid >> 6, lane = tid & 63;
    const int q = lane >> 4, lr = lane & 15;
    const int m0 = blockIdx.x * 64;

    floatx4 acc[3];
#pragma unroll
    for (int j = 0; j < 3; ++j) acc[j] = (floatx4){0.f, 0.f, 0.f, 0.f};

    const int ra = wave * 16 + (lane >> 2);
    const int ca = (lane & 3) * 8;

    for (int kt = 0; kt < (Esz >> 5); ++kt) {
        const int k0 = kt << 5;
        __syncthreads();
        async_ld16(&xc[(size_t)(m0 + ra) * Esz + k0 + ca], &sA[wave * 512]);
        if (wave < 3)
            async_ld16(&Wb[(size_t)ra * Esz + k0 + ca], &sW[wave * 512]);
        __syncthreads();

        short8 af = *(const short8*)&sA[(wave * 16 + lr) * 32 + q * 8];
#pragma unroll
        for (int j = 0; j < 3; ++j) {
            short8 wf = *(const short8*)&sW[(j * 16 + lr) * 32 + q * 8];
            acc[j] = __builtin_amdgcn_mfma_f32_16x16x32_bf16(af, wf, acc[j], 0, 0, 0);
        }
    }

    const int row = m0 + wave * 16 + q * 4;
    const float bb = Bb[lr], cbv = Cb[lr], db = Db[lr];
#pragma unroll
    for (int r = 0; r < 4; ++r) {
        const float bt = acc[0][r] + bb;
        const float ct = acc[1][r] + cbv;
        const float dt = acc[2][r] + db;
        u [(size_t)(row + r) * Ssz + lr] = bt * dt;
        Ct[(size_t)(row + r) * Ssz + lr] = ct;
    }
}

// ---------------------------------------------------------------------------
// Sequential SSM scan (decay computed inline from rowsum).  One block/batch.
// ---------------------------------------------------------------------------
__global__ void scan_k(const float* __restrict__ rowsum, const float* __restrict__ u,
                       const float* __restrict__ Ct, float* __restrict__ ys) {
    const int b = blockIdx.x;
    const int tid = threadIdx.x;
    const int lane = tid & 63, wave = tid >> 6;
    __shared__ __align__(16) float su[256 * Ssz];
    __shared__ __align__(16) float sc[256 * Ssz];
    __shared__ float sp[256 * 17];
    __shared__ float sd[256];
    float st = 0.f;
    for (int t0 = 0; t0 < Tsz; t0 += 256) {
        __syncthreads();
        const float4* ub = (const float4*)(u  + ((size_t)b * Tsz + t0) * Ssz);
        const float4* cb = (const float4*)(Ct + ((size_t)b * Tsz + t0) * Ssz);
#pragma unroll
        for (int i = 0; i < 4; ++i) {
            ((float4*)su)[tid + i * 256] = ub[tid + i * 256];
            ((float4*)sc)[tid + i * 256] = cb[tid + i * 256];
        }
        {
            const float m = rowsum[b * Tsz + t0 + tid] * (1.f / (float)Esz);
            sd[tid] = expf(fminf(fmaxf(-m, -10.f), 10.f));
        }
        __syncthreads();
        if (wave == 0 && lane < 16) {
#pragma unroll 8
            for (int i = 0; i < 256; ++i) {
                st = st * sd[i] + su[i * Ssz + lane];
                sp[i * 17 + lane] = sc[i * Ssz + lane] * st;
            }
        }
        __syncthreads();
        float s = 0.f;
#pragma unroll
        for (int j = 0; j < 16; ++j) s += sp[tid * 17 + j];
        ys[b * Tsz + t0 + tid] = s;
    }
}

// ---------------------------------------------------------------------------
extern "C" void kernel_launch(void* const* d_in, const int* in_sizes, int n_in,
                              void* d_out, int out_size, void* d_ws, size_t ws_size,
                              hipStream_t stream) {
    const float* x      = (const float*)d_in[0];
    const float* in_w   = (const float*)d_in[1];
    const float* in_b   = (const float*)d_in[2];
    const float* conv_w = (const float*)d_in[3];
    const float* conv_b = (const float*)d_in[4];
    const float* dt_w   = (const float*)d_in[5];
    const float* dt_b   = (const float*)d_in[6];
    const float* B_w    = (const float*)d_in[7];
    const float* B_b    = (const float*)d_in[8];
    const float* C_w    = (const float*)d_in[9];
    const float* C_b    = (const float*)d_in[10];
    const float* D_w    = (const float*)d_in[11];
    const float* D_b    = (const float*)d_in[12];
    const float* out_w  = (const float*)d_in[13];
    const float* out_b  = (const float*)d_in[14];
    float* out = (float*)d_out;

    char* ws = (char*)d_ws;
    auto alloc = [&](size_t bytes) {
        char* p = ws;
        ws += (bytes + 255) & ~(size_t)255;
        return p;
    };
    __hip_bfloat16* x_bf   = (__hip_bfloat16*)alloc((size_t)Mrows * Dsz * 2);     // 16 MB
    __hip_bfloat16* inw_bf = (__hip_bfloat16*)alloc((size_t)2 * Esz * Dsz * 2);   //  8 MB
    __hip_bfloat16* dtw_bf = (__hip_bfloat16*)alloc((size_t)Esz * Esz * 2);       //  8 MB
    __hip_bfloat16* outw_bf= (__hip_bfloat16*)alloc((size_t)Dsz * Esz * 2);       //  4 MB
    __hip_bfloat16* xp_bf  = (__hip_bfloat16*)alloc((size_t)Mrows * 2 * Esz * 2); // 64 MB
    __hip_bfloat16* xc_bf  = (__hip_bfloat16*)alloc((size_t)Mrows * Esz * 2);     // 32 MB
    __hip_bfloat16* s_bf   = (__hip_bfloat16*)alloc((size_t)Mrows * Esz * 2);     // 32 MB
    __hip_bfloat16* wb_bf  = (__hip_bfloat16*)alloc((size_t)48 * Esz * 2);
    float* rowsum = (float*)alloc(Mrows * 4);
    float* u_buf  = (float*)alloc((size_t)Mrows * Ssz * 4);
    float* ct_buf = (float*)alloc((size_t)Mrows * Ssz * 4);
    float* ys_buf = (float*)alloc(Mrows * 4);
    (void)alloc(131072);           // pad: staging tail over-reads stay inside ws

    hipMemsetAsync(rowsum, 0, Mrows * 4, stream);

    // conversions: x/in_w/dt_w/out_w -> bf16
    cvt_all<<<4608, 256, 0, stream>>>((const float4*)x, (const float4*)in_w,
                                      (const float4*)dt_w, (const float4*)out_w,
                                      (ushort4v*)x_bf, (ushort4v*)inw_bf,
                                      (ushort4v*)dtw_bf, (ushort4v*)outw_bf);
    pack_bcd<<<48 * Esz / 256, 256, 0, stream>>>(B_w, C_w, D_w, wb_bf);

    // GEMM1 (bf16 m97): xp = x @ in_w^T + in_b  (8192x4096x1024) -> bf16
    gemm_bf<0><<<dim3(4096 / 128, Mrows / 128), 256, 0, stream>>>(
        (const unsigned char*)x_bf, (const unsigned char*)inw_bf, in_b,
        Mrows, 4096, 1024, xp_bf, nullptr, nullptr, nullptr, nullptr);

    // fused conv+SiLU (-> xc bf16) + gate SiLU (-> S bf16)
    conv_gate_k<<<(Mrows * Esz / 8) / 256, 256, 0, stream>>>(
        xp_bf, conv_w, conv_b, xc_bf, s_bf);

    // GEMM2 (bf16 m97): softplus(xc @ dt_w^T + dt_b) row-sums (8192x2048x2048)
    gemm_bf<1><<<dim3(Esz / 128, Mrows / 128), 256, 0, stream>>>(
        (const unsigned char*)xc_bf, (const unsigned char*)dtw_bf, dt_b,
        Mrows, Esz, Esz, nullptr, rowsum, nullptr, nullptr, nullptr);

    // B/C/D projections + u = Bt*Dt (bf16 xc)
    bcd_mfma<<<Mrows / 64, 256, 0, stream>>>(xc_bf, wb_bf, B_b, C_b, D_b, u_buf, ct_buf);

    // sequential scan (decay inline) -> ys
    scan_k<<<Bsz, 256, 0, stream>>>(rowsum, u_buf, ct_buf, ys_buf);

    // GEMM3 (bf16 m97): out = x + ys[row]*(S @ out_w^T) + out_b (8192x1024x2048)
    gemm_bf<2><<<dim3(Dsz / 128, Mrows / 128), 256, 0, stream>>>(
        (const unsigned char*)s_bf, (const unsigned char*)outw_bf, out_b,
        Mrows, Dsz, Esz, nullptr, nullptr, x, ys_buf, out);
}

// Round 6
// 503.211 us; speedup vs baseline: 1.0167x; 1.0167x over previous
//
#include <hip/hip_runtime.h>
#include <hip/hip_bf16.h>

// Problem constants
#define Bsz 4
#define Tsz 2048
#define Dsz 1024
#define Ssz 16
#define Esz 2048
#define Mrows (Bsz*Tsz)        // 8192

typedef __attribute__((ext_vector_type(8))) short short8;
typedef __attribute__((ext_vector_type(4))) float floatx4;
typedef __attribute__((ext_vector_type(4))) unsigned short ushort4v;

__device__ __forceinline__ void async_ld16(const void* g, void* l) {
    __builtin_amdgcn_global_load_lds(
        (const __attribute__((address_space(1))) void*)g,
        (__attribute__((address_space(3))) void*)l,
        16, 0, 0);
}

__device__ __forceinline__ float sigmoidf_(float v) { return 1.f / (1.f + expf(-v)); }
__device__ __forceinline__ float bf2f(unsigned short u) {
    union { unsigned u32; float f; } c; c.u32 = (unsigned)u << 16; return c.f;
}
__device__ __forceinline__ unsigned short f2bf(float f) {
    __hip_bfloat16 h = __float2bfloat16(f);
    return *(unsigned short*)&h;
}

// s_waitcnt immediates (gfx9): vm[3:0]|exp[6:4]|lgkm[11:8]|vm[15:14]
#define WAIT_VM(N)   (0xF70 | (N))

// ---------------------------------------------------------------------------
// merged conversions to bf16: x, in_w, dt_w, out_w.
// ---------------------------------------------------------------------------
#define CV_S0 2097152   // x:     8388608 f32 / 4
#define CV_S1 3145728   // in_w: +4194304 / 4
#define CV_S2 4194304   // dt_w: +4194304 / 4
#define CV_S3 4718592   // out_w:+2097152 / 4
__global__ void cvt_all(const float4* __restrict__ x,  const float4* __restrict__ iw,
                        const float4* __restrict__ dw, const float4* __restrict__ ow,
                        ushort4v* __restrict__ xb, ushort4v* __restrict__ iwb,
                        ushort4v* __restrict__ dwb, ushort4v* __restrict__ owb) {
    int i = blockIdx.x * blockDim.x + threadIdx.x;
    const int stride = gridDim.x * blockDim.x;
    for (; i < CV_S3; i += stride) {
        float4 v; ushort4v* dst; int j;
        if (i < CV_S0)      { j = i;         v = x[j];  dst = xb; }
        else if (i < CV_S1) { j = i - CV_S0; v = iw[j]; dst = iwb; }
        else if (i < CV_S2) { j = i - CV_S1; v = dw[j]; dst = dwb; }
        else                { j = i - CV_S2; v = ow[j]; dst = owb; }
        ushort4v o;
        o[0] = f2bf(v.x); o[1] = f2bf(v.y); o[2] = f2bf(v.z); o[3] = f2bf(v.w);
        dst[j] = o;
    }
}

// ---------------------------------------------------------------------------
// R6: 256x256 8-wave bf16 GEMM with counted-vmcnt phase pipeline (T3+T4+T5).
// Rationale: 2-phase wall (m233) confirmed across 6 variants; escape is
// phase-split + counted waits (m218 +38-73%).  A faithful 2-stage dbuf port
// cannot avoid vmcnt(0) for its last-staged half (derived), so this uses a
// 3-DEEP LDS stage rotation (3 x (A16KB + B16KB) = 96KB) giving every DMA
// >=2 phases of latency cover with vmcnt(2) ONCE per K-tile, never 0.
// Geometry: BM=BN=256, BK=32 bf16 (64B rows), 512 thr = 8 waves (2M x 4N),
// wave tile 128x64 (mf=8, nf=4), acc 8x4 floatx4 = 128 VGPR.
// Per K-tile t (2 phases, stage sr=t%3, staging tile t+2 into sw=(t+2)%3):
//  phA: ds_read B[4]+A[mf0-3] (8 b128); issue B(t+2) (2 loads); barrier;
//       setprio(1) 16 MFMA setprio(0); barrier.
//  phB: ds_read A[mf4-7] (4); vmcnt(2)+clobber (certifies tile t+1: only
//       B(t+2) may float); issue A(t+2); barrier; 16 MFMA; barrier.
// Write-safety: region (t+2)%3's occupant t-1 reads complete at barrier2 of
// its last phase, >=1 full phase before the overwrite issues (lockstep via
// double barriers).  LDS chunk-XOR slot = q ^ ((row>>1)&3) on BOTH the
// global source (pre-swizzle) and the read address: full-wave balanced
// b128 (8 slots x 8 lanes).
// MODE: 0 bf16 store+bias, 1 softplus rowsum.
// ---------------------------------------------------------------------------
template<int MODE>
__launch_bounds__(512, 1)
__global__ void gemm256_bf(const unsigned char* __restrict__ A,
                           const unsigned char* __restrict__ Bw,
                           const float* __restrict__ bias,
                           int N, int K,
                           __hip_bfloat16* __restrict__ outb,
                           float* __restrict__ rowsum) {
    __shared__ __align__(16) unsigned char sA[3 * 16384];  // 3 x 256 rows x 64B
    __shared__ __align__(16) unsigned char sB[3 * 16384];

    const int tid  = threadIdx.x;
    const int wave = tid >> 6, lane = tid & 63;
    const int wm = wave >> 2, wn = wave & 3;      // 2M x 4N wave grid
    const int q = lane >> 4, lr = lane & 15;
    const int swz = (lr >> 1) & 3;

    // XCD-aware remap: each XCD owns a contiguous M-stripe (gy % 8 == 0).
    const int gx = gridDim.x, gy = gridDim.y;
    const int flat = blockIdx.y * gx + blockIdx.x;
    const int stripe = gy >> 3;
    const int xcd = flat & 7, local = flat >> 3;
    const int mt = xcd * stripe + (local % stripe);
    const int nt = local / stripe;
    const int m0 = mt * 256, n0 = nt * 256;

    floatx4 acc[8][4];
#pragma unroll
    for (int i = 0; i < 8; ++i)
#pragma unroll
        for (int j = 0; j < 4; ++j) acc[i][j] = (floatx4){0.f, 0.f, 0.f, 0.f};

    // staging: 16KB per matrix per K-tile = 1024 chunks; thread does 2.
    // idx = j*512+tid -> row = idx>>2, chunk = idx&3; source pre-swizzled:
    // global chunk (ch ^ ((row>>1)&3)) lands at linear LDS slot ch.
    const size_t rbytes = (size_t)K * 2;
    const unsigned char* pa[2];
    const unsigned char* pb[2];
    int ldso[2];
#pragma unroll
    for (int j = 0; j < 2; ++j) {
        const int idx = j * 512 + tid, row = idx >> 2, ch = idx & 3;
        const int col = (ch ^ ((row >> 1) & 3)) * 16;
        pa[j] = A  + (size_t)(m0 + row) * rbytes + col;
        pb[j] = Bw + (size_t)(n0 + row) * rbytes + col;
        ldso[j] = idx * 16;
    }

    // fragment read offsets (within a 16KB stage): row*64 + (q^swz)*16
    const int fA = (wm * 128 + lr) * 64 + ((q ^ swz) * 16);   // + mf*1024
    const int fB = (wn * 64  + lr) * 64 + ((q ^ swz) * 16);   // + nf*1024

#define STAGE_A(SW) do {                                          \
        async_ld16(pa[0], &sA[(SW) * 16384 + ldso[0]]);           \
        async_ld16(pa[1], &sA[(SW) * 16384 + ldso[1]]);           \
        pa[0] += 64; pa[1] += 64;                                 \
    } while (0)
#define STAGE_B(SW) do {                                          \
        async_ld16(pb[0], &sB[(SW) * 16384 + ldso[0]]);           \
        async_ld16(pb[1], &sB[(SW) * 16384 + ldso[1]]);           \
        pb[0] += 64; pb[1] += 64;                                 \
    } while (0)

    // prologue: tiles 0 and 1 -> stages 0, 1; certify tile 0 (vmcnt(4):
    // B1,A1 may still float), barrier publishes.
    STAGE_B(0); STAGE_A(0);
    STAGE_B(1); STAGE_A(1);
    __builtin_amdgcn_s_waitcnt(WAIT_VM(4));
    asm volatile("" ::: "memory");
    __builtin_amdgcn_s_barrier();

    const int NT = K >> 5;         // K-tiles of 32 elements
    int sr = 0, sw = 2;
    for (int t = 0; t < NT; ++t) {
        const int rA = sr * 16384, rB = sr * 16384;
        // ---- phase A: B all + A mf0-3 ----
        short8 b8[4], a8[4];
#pragma unroll
        for (int nf = 0; nf < 4; ++nf)
            b8[nf] = *(const short8*)&sB[rB + fB + nf * 1024];
#pragma unroll
        for (int mf = 0; mf < 4; ++mf)
            a8[mf] = *(const short8*)&sA[rA + fA + mf * 1024];
        STAGE_B(sw);               // tile t+2 (tail: garbage, never read)
        __builtin_amdgcn_s_barrier();
        __builtin_amdgcn_s_setprio(1);
#pragma unroll
        for (int mf = 0; mf < 4; ++mf)
#pragma unroll
            for (int nf = 0; nf < 4; ++nf)
                acc[mf][nf] = __builtin_amdgcn_mfma_f32_16x16x32_bf16(
                    a8[mf], b8[nf], acc[mf][nf], 0, 0, 0);
        __builtin_amdgcn_s_setprio(0);
        __builtin_amdgcn_s_barrier();

        // ---- phase B: A mf4-7 ----
        short8 a8h[4];
#pragma unroll
        for (int mf = 0; mf < 4; ++mf)
            a8h[mf] = *(const short8*)&sA[rA + fA + (mf + 4) * 1024];
        __builtin_amdgcn_s_waitcnt(WAIT_VM(2));   // certify tile t+1
        asm volatile("" ::: "memory");
        STAGE_A(sw);               // tile t+2
        __builtin_amdgcn_s_barrier();
        __builtin_amdgcn_s_setprio(1);
#pragma unroll
        for (int mf = 0; mf < 4; ++mf)
#pragma unroll
            for (int nf = 0; nf < 4; ++nf)
                acc[mf + 4][nf] = __builtin_amdgcn_mfma_f32_16x16x32_bf16(
                    a8h[mf], b8[nf], acc[mf + 4][nf], 0, 0, 0);
        __builtin_amdgcn_s_setprio(0);
        __builtin_amdgcn_s_barrier();

        sr = (sr == 2) ? 0 : sr + 1;
        sw = (sw == 2) ? 0 : sw + 1;
    }
#undef STAGE_A
#undef STAGE_B
    __builtin_amdgcn_s_waitcnt(WAIT_VM(0));       // drain garbage tail tiles

    // epilogue: C/D layout col = lane&15, row = (lane>>4)*4 + reg
    if (MODE == 0) {
#pragma unroll
        for (int i = 0; i < 8; ++i) {
            const int row = m0 + wm * 128 + i * 16 + q * 4;
#pragma unroll
            for (int j = 0; j < 4; ++j) {
                const int col = n0 + wn * 64 + j * 16 + lr;
                const float bc = bias[col];
#pragma unroll
                for (int r = 0; r < 4; ++r)
                    outb[(size_t)(row + r) * N + col] = __float2bfloat16(acc[i][j][r] + bc);
            }
        }
    } else {
#pragma unroll
        for (int i = 0; i < 8; ++i) {
            float rs[4] = {0.f, 0.f, 0.f, 0.f};
#pragma unroll
            for (int j = 0; j < 4; ++j) {
                const int col = n0 + wn * 64 + j * 16 + lr;
                const float bc = bias[col];
#pragma unroll
                for (int r = 0; r < 4; ++r) {
                    float v = acc[i][j][r] + bc;
                    float sp = (v > 20.f) ? v : log1pf(expf(v));
                    rs[r] += sp;
                }
            }
#pragma unroll
            for (int r = 0; r < 4; ++r) {
                float v = rs[r];
                v += __shfl_xor(v, 1); v += __shfl_xor(v, 2);
                v += __shfl_xor(v, 4); v += __shfl_xor(v, 8);
                if (lr == 0)
                    atomicAdd(&rowsum[m0 + wm * 128 + i * 16 + q * 4 + r], v);
            }
        }
    }
}

// ---------------------------------------------------------------------------
// m97-style 128x128 bf16 GEMM (R5 structure) — kept for GEMM3 (N=1024 would
// idle half the machine at 256² tiles).  MODE 2: fp32 resid+ys*acc+bias.
// ---------------------------------------------------------------------------
template<int MODE>
__launch_bounds__(256, 3)
__global__ void gemm_bf(const unsigned char* __restrict__ A,
                        const unsigned char* __restrict__ Bw,
                        const float* __restrict__ bias,
                        int M, int N, int K,
                        __hip_bfloat16* __restrict__ outb,
                        float* __restrict__ rowsum,
                        const float* __restrict__ resid,
                        const float* __restrict__ ysv,
                        float* __restrict__ outf) {
    __shared__ __align__(16) unsigned char sA[2 * 8192];   // 128 rows x 64B
    __shared__ __align__(16) unsigned char sB[2 * 8192];

    const int tid  = threadIdx.x;
    const int wave = tid >> 6, lane = tid & 63;
    const int wm = wave >> 1, wn = wave & 1;
    const int q = lane >> 4, lr = lane & 15;

    const int gx = gridDim.x, gy = gridDim.y;
    const int flat = blockIdx.y * gx + blockIdx.x;
    const int stripe = gy >> 3;
    const int xcd = flat & 7, local = flat >> 3;
    const int mt = xcd * stripe + (local % stripe);
    const int nt = local / stripe;
    const int m0 = mt * 128, n0 = nt * 128;

    floatx4 acc[4][4];
#pragma unroll
    for (int i = 0; i < 4; ++i)
#pragma unroll
        for (int j = 0; j < 4; ++j) acc[i][j] = (floatx4){0.f, 0.f, 0.f, 0.f};

    const size_t rbytes = (size_t)K * 2;
    const unsigned char* pa[2];
    const unsigned char* pb[2];
#pragma unroll
    for (int i = 0; i < 2; ++i) {
        const int idx = i * 256 + tid, row = idx >> 2, ch = idx & 3;
        pa[i] = A  + (size_t)(m0 + row) * rbytes + ch * 16;
        pb[i] = Bw + (size_t)(n0 + row) * rbytes + ch * 16;
    }

    const int oA = (wm * 64 + lr) * 64 + q * 16;
    const int oB = (wn * 64 + lr) * 64 + q * 16;

#define BF_ISSUE(ST) do {                                                      \
        _Pragma("unroll")                                                      \
        for (int i = 0; i < 2; ++i) {                                          \
            async_ld16(pa[i], &sA[(ST) * 8192 + (i * 256 + wave * 64) * 16]);  \
            pa[i] += 64;                                                       \
        }                                                                      \
        _Pragma("unroll")                                                      \
        for (int i = 0; i < 2; ++i) {                                          \
            async_ld16(pb[i], &sB[(ST) * 8192 + (i * 256 + wave * 64) * 16]);  \
            pb[i] += 64;                                                       \
        }                                                                      \
    } while (0)

    const int ntile = K >> 5;
    BF_ISSUE(0);
    for (int kt = 0; kt < ntile; ++kt) {
        const int st = kt & 1;
        const int base = st * 8192;
        __builtin_amdgcn_s_waitcnt(WAIT_VM(0));
        __syncthreads();
        BF_ISSUE(st ^ 1);

        short8 a8[4], b8[4];
#pragma unroll
        for (int i = 0; i < 4; ++i)
            a8[i] = *(const short8*)&sA[base + oA + i * 1024];
#pragma unroll
        for (int j = 0; j < 4; ++j)
            b8[j] = *(const short8*)&sB[base + oB + j * 1024];
#pragma unroll
        for (int i = 0; i < 4; ++i)
#pragma unroll
            for (int j = 0; j < 4; ++j)
                acc[i][j] = __builtin_amdgcn_mfma_f32_16x16x32_bf16(
                    a8[i], b8[j], acc[i][j], 0, 0, 0);
    }
#undef BF_ISSUE
    __builtin_amdgcn_s_waitcnt(WAIT_VM(0));

    if (MODE == 0) {
#pragma unroll
        for (int i = 0; i < 4; ++i) {
            const int row = m0 + wm * 64 + i * 16 + q * 4;
#pragma unroll
            for (int j = 0; j < 4; ++j) {
                const int col = n0 + wn * 64 + j * 16 + lr;
                const float bc = bias[col];
#pragma unroll
                for (int r = 0; r < 4; ++r)
                    outb[(size_t)(row + r) * N + col] = __float2bfloat16(acc[i][j][r] + bc);
            }
        }
    } else if (MODE == 1) {
#pragma unroll
        for (int i = 0; i < 4; ++i) {
            float rs[4] = {0.f, 0.f, 0.f, 0.f};
#pragma unroll
            for (int j = 0; j < 4; ++j) {
                const int col = n0 + wn * 64 + j * 16 + lr;
                const float bc = bias[col];
#pragma unroll
                for (int r = 0; r < 4; ++r) {
                    float v = acc[i][j][r] + bc;
                    float sp = (v > 20.f) ? v : log1pf(expf(v));
                    rs[r] += sp;
                }
            }
#pragma unroll
            for (int r = 0; r < 4; ++r) {
                float v = rs[r];
                v += __shfl_xor(v, 1); v += __shfl_xor(v, 2);
                v += __shfl_xor(v, 4); v += __shfl_xor(v, 8);
                if (lr == 0)
                    atomicAdd(&rowsum[m0 + wm * 64 + i * 16 + q * 4 + r], v);
            }
        }
    } else {
#pragma unroll
        for (int i = 0; i < 4; ++i) {
            const int row = m0 + wm * 64 + i * 16 + q * 4;
#pragma unroll
            for (int j = 0; j < 4; ++j) {
                const int col = n0 + wn * 64 + j * 16 + lr;
                const float bc = bias[col];
#pragma unroll
                for (int r = 0; r < 4; ++r) {
                    const size_t idx = (size_t)(row + r) * N + col;
                    outf[idx] = resid[idx] + ysv[row + r] * acc[i][j][r] + bc;
                }
            }
        }
    }
}

// ---------------------------------------------------------------------------
// fused elementwise pass over xp: depthwise conv(k=3)+bias+SiLU on main half
// -> xc (bf16); SiLU on gate half -> S (bf16).
// ---------------------------------------------------------------------------
__global__ void conv_gate_k(const __hip_bfloat16* __restrict__ xp,
                            const float* __restrict__ cw,
                            const float* __restrict__ cb,
                            __hip_bfloat16* __restrict__ xc,
                            __hip_bfloat16* __restrict__ sgate) {
    const int idx8 = blockIdx.x * blockDim.x + threadIdx.x;
    const int e = (idx8 & (Esz / 8 - 1)) * 8;
    const int r = idx8 >> 8;
    const int t = r & (Tsz - 1);
    const unsigned short* row0 = (const unsigned short*)(xp + (size_t)r * (2 * Esz) + e);
    short8 vm1 = (t > 0)       ? *(const short8*)(row0 - 2 * Esz) : (short8){0,0,0,0,0,0,0,0};
    short8 v00 = *(const short8*)row0;
    short8 vp1 = (t < Tsz - 1) ? *(const short8*)(row0 + 2 * Esz) : (short8){0,0,0,0,0,0,0,0};
    short8 o;
#pragma unroll
    for (int k = 0; k < 8; ++k) {
        const int ek = e + k;
        float v = bf2f((unsigned short)vm1[k]) * cw[ek * 3 + 0]
                + bf2f((unsigned short)v00[k]) * cw[ek * 3 + 1]
                + bf2f((unsigned short)vp1[k]) * cw[ek * 3 + 2] + cb[ek];
        float sil = v * sigmoidf_(v);
        o[k] = (short)f2bf(sil);
    }
    *(short8*)(xc + (size_t)idx8 * 8) = o;

    short8 g = *(const short8*)(row0 + Esz);
    short8 os;
#pragma unroll
    for (int k = 0; k < 8; ++k) {
        const float gv = bf2f((unsigned short)g[k]);
        os[k] = (short)f2bf(gv * sigmoidf_(gv));
    }
    *(short8*)(sgate + (size_t)idx8 * 8) = os;
}

// ---------------------------------------------------------------------------
// pack B_w/C_w/D_w (each [16,2048] fp32) into Wb [48,2048] bf16
// ---------------------------------------------------------------------------
__global__ void pack_bcd(const float* __restrict__ Bw, const float* __restrict__ Cw,
                         const float* __restrict__ Dw, __hip_bfloat16* __restrict__ Wb) {
    const int idx = blockIdx.x * blockDim.x + threadIdx.x;
    if (idx >= 48 * Esz) return;
    const int row = idx >> 11, col = idx & (Esz - 1);
    float v;
    if (row < 16)      v = Bw[row * Esz + col];
    else if (row < 32) v = Cw[(row - 16) * Esz + col];
    else               v = Dw[(row - 32) * Esz + col];
    Wb[idx] = __float2bfloat16(v);
}

// ---------------------------------------------------------------------------
// B/C/D projections via MFMA skinny GEMM: xc[M,E] @ Wb[48,E]^T.
// ---------------------------------------------------------------------------
__launch_bounds__(256)
__global__ void bcd_mfma(const __hip_bfloat16* __restrict__ xc,
                         const __hip_bfloat16* __restrict__ Wb,
                         const float* __restrict__ Bb, const float* __restrict__ Cb,
                         const float* __restrict__ Db,
                         float* __restrict__ u, float* __restrict__ Ct) {
    __shared__ __align__(16) __hip_bfloat16 sA[64 * 32];
    __shared__ __align__(16) __hip_bfloat16 sW[48 * 32];
    const int tid = threadIdx.x;
    const int wave = tid >> 6, lane = tid & 63;
    const int q = lane >> 4, lr = lane & 15;
    const int m0 = blockIdx.x * 64;

    floatx4 acc[3];
#pragma unroll
    for (int j = 0; j < 3; ++j) acc[j] = (floatx4){0.f, 0.f, 0.f, 0.f};

    const int ra = wave * 16 + (lane >> 2);
    const int ca = (lane & 3) * 8;

    for (int kt = 0; kt < (Esz >> 5); ++kt) {
        const int k0 = kt << 5;
        __syncthreads();
        async_ld16(&xc[(size_t)(m0 + ra) * Esz + k0 + ca], &sA[wave * 512]);
        if (wave < 3)
            async_ld16(&Wb[(size_t)ra * Esz + k0 + ca], &sW[wave * 512]);
        __syncthreads();

        short8 af = *(const short8*)&sA[(wave * 16 + lr) * 32 + q * 8];
#pragma unroll
        for (int j = 0; j < 3; ++j) {
            short8 wf = *(const short8*)&sW[(j * 16 + lr) * 32 + q * 8];
            acc[j] = __builtin_amdgcn_mfma_f32_16x16x32_bf16(af, wf, acc[j], 0, 0, 0);
        }
    }

    const int row = m0 + wave * 16 + q * 4;
    const float bb = Bb[lr], cbv = Cb[lr], db = Db[lr];
#pragma unroll
    for (int r = 0; r < 4; ++r) {
        const float bt = acc[0][r] + bb;
        const float ct = acc[1][r] + cbv;
        const float dt = acc[2][r] + db;
        u [(size_t)(row + r) * Ssz + lr] = bt * dt;
        Ct[(size_t)(row + r) * Ssz + lr] = ct;
    }
}

// ---------------------------------------------------------------------------
// Sequential SSM scan (decay computed inline from rowsum).  One block/batch.
// ---------------------------------------------------------------------------
__global__ void scan_k(const float* __restrict__ rowsum, const float* __restrict__ u,
                       const float* __restrict__ Ct, float* __restrict__ ys) {
    const int b = blockIdx.x;
    const int tid = threadIdx.x;
    const int lane = tid & 63, wave = tid >> 6;
    __shared__ __align__(16) float su[256 * Ssz];
    __shared__ __align__(16) float sc[256 * Ssz];
    __shared__ float sp[256 * 17];
    __shared__ float sd[256];
    float st = 0.f;
    for (int t0 = 0; t0 < Tsz; t0 += 256) {
        __syncthreads();
        const float4* ub = (const float4*)(u  + ((size_t)b * Tsz + t0) * Ssz);
        const float4* cb = (const float4*)(Ct + ((size_t)b * Tsz + t0) * Ssz);
#pragma unroll
        for (int i = 0; i < 4; ++i) {
            ((float4*)su)[tid + i * 256] = ub[tid + i * 256];
            ((float4*)sc)[tid + i * 256] = cb[tid + i * 256];
        }
        {
            const float m = rowsum[b * Tsz + t0 + tid] * (1.f / (float)Esz);
            sd[tid] = expf(fminf(fmaxf(-m, -10.f), 10.f));
        }
        __syncthreads();
        if (wave == 0 && lane < 16) {
#pragma unroll 8
            for (int i = 0; i < 256; ++i) {
                st = st * sd[i] + su[i * Ssz + lane];
                sp[i * 17 + lane] = sc[i * Ssz + lane] * st;
            }
        }
        __syncthreads();
        float s = 0.f;
#pragma unroll
        for (int j = 0; j < 16; ++j) s += sp[tid * 17 + j];
        ys[b * Tsz + t0 + tid] = s;
    }
}

// ---------------------------------------------------------------------------
extern "C" void kernel_launch(void* const* d_in, const int* in_sizes, int n_in,
                              void* d_out, int out_size, void* d_ws, size_t ws_size,
                              hipStream_t stream) {
    const float* x      = (const float*)d_in[0];
    const float* in_w   = (const float*)d_in[1];
    const float* in_b   = (const float*)d_in[2];
    const float* conv_w = (const float*)d_in[3];
    const float* conv_b = (const float*)d_in[4];
    const float* dt_w   = (const float*)d_in[5];
    const float* dt_b   = (const float*)d_in[6];
    const float* B_w    = (const float*)d_in[7];
    const float* B_b    = (const float*)d_in[8];
    const float* C_w    = (const float*)d_in[9];
    const float* C_b    = (const float*)d_in[10];
    const float* D_w    = (const float*)d_in[11];
    const float* D_b    = (const float*)d_in[12];
    const float* out_w  = (const float*)d_in[13];
    const float* out_b  = (const float*)d_in[14];
    float* out = (float*)d_out;

    char* ws = (char*)d_ws;
    auto alloc = [&](size_t bytes) {
        char* p = ws;
        ws += (bytes + 255) & ~(size_t)255;
        return p;
    };
    __hip_bfloat16* x_bf   = (__hip_bfloat16*)alloc((size_t)Mrows * Dsz * 2);     // 16 MB
    __hip_bfloat16* inw_bf = (__hip_bfloat16*)alloc((size_t)2 * Esz * Dsz * 2);   //  8 MB
    __hip_bfloat16* dtw_bf = (__hip_bfloat16*)alloc((size_t)Esz * Esz * 2);       //  8 MB
    __hip_bfloat16* outw_bf= (__hip_bfloat16*)alloc((size_t)Dsz * Esz * 2);       //  4 MB
    __hip_bfloat16* xp_bf  = (__hip_bfloat16*)alloc((size_t)Mrows * 2 * Esz * 2); // 64 MB
    __hip_bfloat16* xc_bf  = (__hip_bfloat16*)alloc((size_t)Mrows * Esz * 2);     // 32 MB
    __hip_bfloat16* s_bf   = (__hip_bfloat16*)alloc((size_t)Mrows * Esz * 2);     // 32 MB
    __hip_bfloat16* wb_bf  = (__hip_bfloat16*)alloc((size_t)48 * Esz * 2);
    float* rowsum = (float*)alloc(Mrows * 4);
    float* u_buf  = (float*)alloc((size_t)Mrows * Ssz * 4);
    float* ct_buf = (float*)alloc((size_t)Mrows * Ssz * 4);
    float* ys_buf = (float*)alloc(Mrows * 4);
    (void)alloc(131072);           // pad: staging tail over-reads stay inside ws

    hipMemsetAsync(rowsum, 0, Mrows * 4, stream);

    cvt_all<<<4608, 256, 0, stream>>>((const float4*)x, (const float4*)in_w,
                                      (const float4*)dt_w, (const float4*)out_w,
                                      (ushort4v*)x_bf, (ushort4v*)inw_bf,
                                      (ushort4v*)dtw_bf, (ushort4v*)outw_bf);
    pack_bcd<<<48 * Esz / 256, 256, 0, stream>>>(B_w, C_w, D_w, wb_bf);

    // GEMM1 (256² counted-vmcnt): xp = x @ in_w^T + in_b (8192x4096x1024)
    gemm256_bf<0><<<dim3(4096 / 256, Mrows / 256), 512, 0, stream>>>(
        (const unsigned char*)x_bf, (const unsigned char*)inw_bf, in_b,
        4096, 1024, xp_bf, nullptr);

    conv_gate_k<<<(Mrows * Esz / 8) / 256, 256, 0, stream>>>(
        xp_bf, conv_w, conv_b, xc_bf, s_bf);

    // GEMM2 (256² counted-vmcnt): softplus(xc @ dt_w^T + dt_b) row-sums
    gemm256_bf<1><<<dim3(Esz / 256, Mrows / 256), 512, 0, stream>>>(
        (const unsigned char*)xc_bf, (const unsigned char*)dtw_bf, dt_b,
        Esz, Esz, nullptr, rowsum);

    bcd_mfma<<<Mrows / 64, 256, 0, stream>>>(xc_bf, wb_bf, B_b, C_b, D_b, u_buf, ct_buf);

    scan_k<<<Bsz, 256, 0, stream>>>(rowsum, u_buf, ct_buf, ys_buf);

    // GEMM3 (128² m97, proven): out = x + ys[row]*(S @ out_w^T) + out_b
    gemm_bf<2><<<dim3(Dsz / 128, Mrows / 128), 256, 0, stream>>>(
        (const unsigned char*)s_bf, (const unsigned char*)outw_bf, out_b,
        Mrows, Dsz, Esz, nullptr, nullptr, x, ys_buf, out);
}

// Round 7
// 385.744 us; speedup vs baseline: 1.3263x; 1.3045x over previous
//
#include <hip/hip_runtime.h>
#include <hip/hip_bf16.h>

// Problem constants
#define Bsz 4
#define Tsz 2048
#define Dsz 1024
#define Ssz 16
#define Esz 2048
#define Mrows (Bsz*Tsz)        // 8192

typedef __attribute__((ext_vector_type(8))) short short8;
typedef __attribute__((ext_vector_type(4))) float floatx4;
typedef __attribute__((ext_vector_type(8))) int int8v;
typedef __attribute__((ext_vector_type(4))) int int4v;

__device__ __forceinline__ void async_ld16(const void* g, void* l) {
    __builtin_amdgcn_global_load_lds(
        (const __attribute__((address_space(1))) void*)g,
        (__attribute__((address_space(3))) void*)l,
        16, 0, 0);
}

__device__ __forceinline__ float sigmoidf_(float v) { return 1.f / (1.f + expf(-v)); }
__device__ __forceinline__ float bf2f(unsigned short u) {
    union { unsigned u32; float f; } c; c.u32 = (unsigned)u << 16; return c.f;
}
__device__ __forceinline__ int pk_fp8x4(float a, float b, float c, float d) {
    int lo = __builtin_amdgcn_cvt_pk_fp8_f32(a, b, 0, 0);
    int hi = __builtin_amdgcn_cvt_pk_fp8_f32(c, d, 0, 0);
    return (lo & 0xFFFF) | (hi << 16);
}

// s_waitcnt immediates (gfx9): vm[3:0]|exp[6:4]|lgkm[11:8]|vm[15:14]
#define WAIT_VM(N)   (0xF70 | (N))
#define WAIT_LGKM(N) (0xC07F | ((N) << 8))

// ---------------------------------------------------------------------------
// merged conversions: x -> fp8 (x1), in_w -> fp8 (x64), dt_w -> fp8 (x64),
// out_w -> fp8 (x64).  (R7: reverted to the best-measured R1 pipeline; the
// GEMM shape-regime wall is real — m102 curve gives 320 TF for the good bf16
// kernel at 2048-class shapes; our fp8 ~640 TF is above it.  This round
// attacks the ~150us auxiliary tail instead: bcd + scan rewrites.)
// ---------------------------------------------------------------------------
#define CV_S0 2097152   // x:     8388608 f32 / 4
#define CV_S1 3145728   // in_w: +4194304 / 4
#define CV_S2 4194304   // dt_w: +4194304 / 4
#define CV_S3 4718592   // out_w:+2097152 / 4
__global__ void cvt_all(const float4* __restrict__ x,  const float4* __restrict__ iw,
                        const float4* __restrict__ dw, const float4* __restrict__ ow,
                        int* __restrict__ x8, int* __restrict__ iw8,
                        int* __restrict__ dw8, int* __restrict__ ow8) {
    int i = blockIdx.x * blockDim.x + threadIdx.x;
    const int stride = gridDim.x * blockDim.x;
    for (; i < CV_S3; i += stride) {
        if (i < CV_S0) {
            float4 v = x[i];
            x8[i] = pk_fp8x4(v.x, v.y, v.z, v.w);
        } else if (i < CV_S1) {
            const int j = i - CV_S0;
            float4 v = iw[j];
            iw8[j] = pk_fp8x4(v.x * 64.f, v.y * 64.f, v.z * 64.f, v.w * 64.f);
        } else if (i < CV_S2) {
            const int j = i - CV_S1;
            float4 v = dw[j];
            dw8[j] = pk_fp8x4(v.x * 64.f, v.y * 64.f, v.z * 64.f, v.w * 64.f);
        } else {
            const int j = i - CV_S2;
            float4 v = ow[j];
            ow8[j] = pk_fp8x4(v.x * 64.f, v.y * 64.f, v.z * 64.f, v.w * 64.f);
        }
    }
}

// ---------------------------------------------------------------------------
// MX-fp8 GEMM (R1-proven, best measured: 104.9us at 8192x2048x2048).
// 128x128 tile, BK=128B, 4 waves 2x2, per-wave 64x64 via 4x4
// mfma_scale_f32_16x16x128_f8f6f4; 2-stage LDS, dist-2 DMA prefetch,
// vmcnt(8) in-loop, mod-8 XOR chunk swizzle.
// MODE: 0 bf16 store, 1 softplus rowsum, 2 fp32 resid + ys[row]*acc.
// ---------------------------------------------------------------------------
template<int MODE, int SA, int SB>
__launch_bounds__(256, 2)
__global__ void gemm_f8(const unsigned char* __restrict__ A,
                        const unsigned char* __restrict__ Bw,
                        const float* __restrict__ bias,
                        int M, int N, int K,
                        __hip_bfloat16* __restrict__ outb,
                        float* __restrict__ rowsum,
                        const float* __restrict__ resid,
                        const float* __restrict__ ysv,
                        float* __restrict__ outf) {
    __shared__ __align__(16) unsigned char sA[2 * 16384];  // 128 rows x 128B
    __shared__ __align__(16) unsigned char sB[2 * 16384];

    const int tid  = threadIdx.x;
    const int wave = tid >> 6, lane = tid & 63;
    const int wm = wave >> 1, wn = wave & 1;
    const int q = lane >> 4, lr = lane & 15;

    // XCD-aware remap: each XCD owns a contiguous M-stripe.
    const int gx = gridDim.x, gy = gridDim.y;
    const int flat = blockIdx.y * gx + blockIdx.x;
    const int stripe = gy >> 3;
    const int xcd = flat & 7, local = flat >> 3;
    const int mt = xcd * stripe + (local % stripe);
    const int nt = local / stripe;
    const int m0 = mt * 128, n0 = nt * 128;

    floatx4 acc[4][4];
#pragma unroll
    for (int i = 0; i < 4; ++i)
#pragma unroll
        for (int j = 0; j < 4; ++j) acc[i][j] = (floatx4){0.f, 0.f, 0.f, 0.f};

    const unsigned char* pa[4];
    const unsigned char* pb[4];
#pragma unroll
    for (int i = 0; i < 4; ++i) {
        const int idx = i * 256 + tid, row = idx >> 3, s = idx & 7;
        pa[i] = A + (size_t)(m0 + row) * K + ((s ^ (row & 7)) * 16);
        pb[i] = Bw + (size_t)(n0 + row) * K + ((s ^ (row & 7)) * 16);
    }

    const int rA = wm * 64 + lr, rB = wn * 64 + lr;
    const int oA0 = rA * 128 + (((2 * q)     ^ (rA & 7)) * 16);
    const int oA1 = rA * 128 + (((2 * q + 1) ^ (rA & 7)) * 16);
    const int oB0 = rB * 128 + (((2 * q)     ^ (rB & 7)) * 16);
    const int oB1 = rB * 128 + (((2 * q + 1) ^ (rB & 7)) * 16);

#define F8_ISSUE(ST) do {                                                      \
        _Pragma("unroll")                                                      \
        for (int i = 0; i < 4; ++i) {                                          \
            async_ld16(pa[i], &sA[(ST) * 16384 + (i * 256 + wave * 64) * 16]); \
            pa[i] += 128;                                                      \
        }                                                                      \
        _Pragma("unroll")                                                      \
        for (int i = 0; i < 4; ++i) {                                          \
            async_ld16(pb[i], &sB[(ST) * 16384 + (i * 256 + wave * 64) * 16]); \
            pb[i] += 128;                                                      \
        }                                                                      \
    } while (0)

#define F8_STEP(ST) do {                                                       \
        asm volatile("" ::: "memory");                                         \
        __builtin_amdgcn_s_waitcnt(WAIT_VM(8));   /* this tile landed */       \
        __builtin_amdgcn_s_barrier();                                          \
        asm volatile("" ::: "memory");                                         \
        int8v a8[4], b8[4];                                                    \
        _Pragma("unroll")                                                      \
        for (int i = 0; i < 4; ++i) {                                          \
            int4v lo = *(const int4v*)&sA[(ST) * 16384 + oA0 + i * 2048];      \
            int4v hi = *(const int4v*)&sA[(ST) * 16384 + oA1 + i * 2048];      \
            a8[i] = __builtin_shufflevector(lo, hi, 0, 1, 2, 3, 4, 5, 6, 7);   \
        }                                                                      \
        _Pragma("unroll")                                                      \
        for (int j = 0; j < 4; ++j) {                                          \
            int4v lo = *(const int4v*)&sB[(ST) * 16384 + oB0 + j * 2048];      \
            int4v hi = *(const int4v*)&sB[(ST) * 16384 + oB1 + j * 2048];      \
            b8[j] = __builtin_shufflevector(lo, hi, 0, 1, 2, 3, 4, 5, 6, 7);   \
        }                                                                      \
        asm volatile("" ::: "memory");                                         \
        __builtin_amdgcn_s_waitcnt(WAIT_LGKM(0)); /* frags landed */           \
        __builtin_amdgcn_s_barrier();             /* stage reusable */         \
        asm volatile("" ::: "memory");                                         \
        F8_ISSUE(ST);                             /* tile kt+2 -> stage ST */  \
        _Pragma("unroll")                                                      \
        for (int i = 0; i < 4; ++i)                                            \
            _Pragma("unroll")                                                  \
            for (int j = 0; j < 4; ++j)                                        \
                acc[i][j] = __builtin_amdgcn_mfma_scale_f32_16x16x128_f8f6f4(  \
                    a8[i], b8[j], acc[i][j], 0, 0, 0, SA, 0, SB);              \
    } while (0)

    const int nit = K >> 8;        // (K/128)/2 double-steps; K mult of 256
    F8_ISSUE(0);
    F8_ISSUE(1);
    for (int it = 0; it < nit; ++it) {
        F8_STEP(0);
        F8_STEP(1);
    }
#undef F8_STEP
#undef F8_ISSUE
    asm volatile("" ::: "memory");
    __builtin_amdgcn_s_waitcnt(WAIT_VM(0));       // drain 2 garbage tail tiles

    // epilogue: C/D layout col = lane&15, row = (lane>>4)*4 + reg
    if (MODE == 0) {
#pragma unroll
        for (int i = 0; i < 4; ++i) {
            const int row = m0 + wm * 64 + i * 16 + q * 4;
#pragma unroll
            for (int j = 0; j < 4; ++j) {
                const int col = n0 + wn * 64 + j * 16 + lr;
                const float bc = bias[col];
#pragma unroll
                for (int r = 0; r < 4; ++r)
                    outb[(size_t)(row + r) * N + col] = __float2bfloat16(acc[i][j][r] + bc);
            }
        }
    } else if (MODE == 1) {
#pragma unroll
        for (int i = 0; i < 4; ++i) {
            float rs[4] = {0.f, 0.f, 0.f, 0.f};
#pragma unroll
            for (int j = 0; j < 4; ++j) {
                const int col = n0 + wn * 64 + j * 16 + lr;
                const float bc = bias[col];
#pragma unroll
                for (int r = 0; r < 4; ++r) {
                    float v = acc[i][j][r] + bc;
                    float sp = (v > 20.f) ? v : log1pf(expf(v));
                    rs[r] += sp;
                }
            }
#pragma unroll
            for (int r = 0; r < 4; ++r) {
                float v = rs[r];
                v += __shfl_xor(v, 1); v += __shfl_xor(v, 2);
                v += __shfl_xor(v, 4); v += __shfl_xor(v, 8);
                if (lr == 0)
                    atomicAdd(&rowsum[m0 + wm * 64 + i * 16 + q * 4 + r], v);
            }
        }
    } else {
#pragma unroll
        for (int i = 0; i < 4; ++i) {
            const int row = m0 + wm * 64 + i * 16 + q * 4;
#pragma unroll
            for (int j = 0; j < 4; ++j) {
                const int col = n0 + wn * 64 + j * 16 + lr;
                const float bc = bias[col];
#pragma unroll
                for (int r = 0; r < 4; ++r) {
                    const size_t idx = (size_t)(row + r) * N + col;
                    outf[idx] = resid[idx] + ysv[row + r] * acc[i][j][r] + bc;
                }
            }
        }
    }
}

// ---------------------------------------------------------------------------
// fused elementwise pass over xp: depthwise conv(k=3)+bias+SiLU on main half
// -> xc (bf16, for bcd) + xc*16 (fp8, GEMM2 A); SiLU on gate half
// -> S*16 (fp8, GEMM3 A).
// ---------------------------------------------------------------------------
__global__ void conv_gate_k(const __hip_bfloat16* __restrict__ xp,
                            const float* __restrict__ cw,
                            const float* __restrict__ cb,
                            __hip_bfloat16* __restrict__ xc,
                            int2* __restrict__ xc8,
                            int2* __restrict__ s8) {
    const int idx8 = blockIdx.x * blockDim.x + threadIdx.x;
    const int e = (idx8 & (Esz / 8 - 1)) * 8;
    const int r = idx8 >> 8;
    const int t = r & (Tsz - 1);
    const unsigned short* row0 = (const unsigned short*)(xp + (size_t)r * (2 * Esz) + e);
    short8 vm1 = (t > 0)       ? *(const short8*)(row0 - 2 * Esz) : (short8){0,0,0,0,0,0,0,0};
    short8 v00 = *(const short8*)row0;
    short8 vp1 = (t < Tsz - 1) ? *(const short8*)(row0 + 2 * Esz) : (short8){0,0,0,0,0,0,0,0};
    short8 o;
    float sil[8];
#pragma unroll
    for (int k = 0; k < 8; ++k) {
        const int ek = e + k;
        float v = bf2f((unsigned short)vm1[k]) * cw[ek * 3 + 0]
                + bf2f((unsigned short)v00[k]) * cw[ek * 3 + 1]
                + bf2f((unsigned short)vp1[k]) * cw[ek * 3 + 2] + cb[ek];
        sil[k] = v * sigmoidf_(v);
        __hip_bfloat16 h = __float2bfloat16(sil[k]);
        o[k] = *(short*)&h;
    }
    *(short8*)(xc + (size_t)idx8 * 8) = o;
    int2 p;
    p.x = pk_fp8x4(sil[0] * 16.f, sil[1] * 16.f, sil[2] * 16.f, sil[3] * 16.f);
    p.y = pk_fp8x4(sil[4] * 16.f, sil[5] * 16.f, sil[6] * 16.f, sil[7] * 16.f);
    xc8[idx8] = p;

    short8 g = *(const short8*)(row0 + Esz);
    float sg[8];
#pragma unroll
    for (int k = 0; k < 8; ++k) {
        const float gv = bf2f((unsigned short)g[k]);
        sg[k] = gv * sigmoidf_(gv);
    }
    int2 ps;
    ps.x = pk_fp8x4(sg[0] * 16.f, sg[1] * 16.f, sg[2] * 16.f, sg[3] * 16.f);
    ps.y = pk_fp8x4(sg[4] * 16.f, sg[5] * 16.f, sg[6] * 16.f, sg[7] * 16.f);
    s8[idx8] = ps;
}

// ---------------------------------------------------------------------------
// pack B_w/C_w/D_w (each [16,2048] fp32) into Wb [48,2048] bf16
// ---------------------------------------------------------------------------
__global__ void pack_bcd(const float* __restrict__ Bw, const float* __restrict__ Cw,
                         const float* __restrict__ Dw, __hip_bfloat16* __restrict__ Wb) {
    const int idx = blockIdx.x * blockDim.x + threadIdx.x;
    if (idx >= 48 * Esz) return;
    const int row = idx >> 11, col = idx & (Esz - 1);
    float v;
    if (row < 16)      v = Bw[row * Esz + col];
    else if (row < 32) v = Cw[(row - 16) * Esz + col];
    else               v = Dw[(row - 32) * Esz + col];
    Wb[idx] = __float2bfloat16(v);
}

// ---------------------------------------------------------------------------
// R7 bcd rewrite: xc[M,E] @ Wb[48,E]^T, 256 blocks x 2 waves, 32 rows/block.
// Wb chunk (48x256 bf16 = 24.5KB) staged once per 256-K (2 barriers/chunk vs
// old 2 barriers/32-K = 8x fewer); A fragments read DIRECTLY from global
// (row-major, 64B runs, L2-friendly) — no A staging, no per-32K sync.
// ---------------------------------------------------------------------------
__launch_bounds__(128)
__global__ void bcd_mfma2(const __hip_bfloat16* __restrict__ xc,
                          const __hip_bfloat16* __restrict__ Wb,
                          const float* __restrict__ Bb, const float* __restrict__ Cb,
                          const float* __restrict__ Db,
                          float* __restrict__ u, float* __restrict__ Ct) {
    __shared__ __align__(16) __hip_bfloat16 sW[48 * 256];   // 24576 B
    const int tid = threadIdx.x;
    const int wave = tid >> 6, lane = tid & 63;
    const int q = lane >> 4, lr = lane & 15;
    const int m0 = blockIdx.x * 32;

    floatx4 acc[3];
#pragma unroll
    for (int j = 0; j < 3; ++j) acc[j] = (floatx4){0.f, 0.f, 0.f, 0.f};

    const __hip_bfloat16* arow = xc + (size_t)(m0 + wave * 16 + lr) * Esz;

    for (int kt = 0; kt < 8; ++kt) {
        const int k0 = kt << 8;
        __syncthreads();                          // prev chunk reads done
        // stage Wb[0:48][k0:k0+256]: 1536 16B-chunks, 12/thread
#pragma unroll
        for (int j = 0; j < 12; ++j) {
            const int idx = j * 128 + tid;
            const int row = idx >> 5, ch = idx & 31;
            async_ld16(&Wb[(size_t)row * Esz + k0 + ch * 8],
                       (__hip_bfloat16*)sW + idx * 8);
        }
        __builtin_amdgcn_s_waitcnt(WAIT_VM(0));
        __syncthreads();                          // chunk visible to all

        short8 af[8];
#pragma unroll
        for (int ks = 0; ks < 8; ++ks)
            af[ks] = *(const short8*)&arow[k0 + ks * 32 + q * 8];
#pragma unroll
        for (int ks = 0; ks < 8; ++ks) {
#pragma unroll
            for (int j = 0; j < 3; ++j) {
                short8 wf = *(const short8*)&sW[(j * 16 + lr) * 256 + ks * 32 + q * 8];
                acc[j] = __builtin_amdgcn_mfma_f32_16x16x32_bf16(af[ks], wf, acc[j], 0, 0, 0);
            }
        }
    }

    const int row = m0 + wave * 16 + q * 4;
    const float bb = Bb[lr], cbv = Cb[lr], db = Db[lr];
#pragma unroll
    for (int r = 0; r < 4; ++r) {
        const float bt = acc[0][r] + bb;
        const float ct = acc[1][r] + cbv;
        const float dt = acc[2][r] + db;
        u [(size_t)(row + r) * Ssz + lr] = bt * dt;
        Ct[(size_t)(row + r) * Ssz + lr] = ct;
    }
}

// ---------------------------------------------------------------------------
// R7 scan rewrite (3 kernels).  decay d_t is SCALAR per (b,t), so chunked
// scan has a cheap fixup: s_t = l_t + P_t*S0  =>  ys_t = ysl_t + P_t*(C_t.S0)
// where l = local scan (zero init), P_t = prod(d) within chunk.
// scanA: 32 blocks (4 batches x 8 chunks of 256), local serial scan.
// scanB: 1 block, serial 8-step combine -> chunk start states.
// scanC: 32 blocks, ys = ysl + P*(C.S0).
// ---------------------------------------------------------------------------
__global__ void scanA(const float* __restrict__ rowsum, const float* __restrict__ u,
                      const float* __restrict__ Ct,
                      float* __restrict__ ysl, float* __restrict__ pt,
                      float* __restrict__ send) {
    const int cid = blockIdx.x;           // 0..31
    const int b = cid >> 3, c = cid & 7;
    const int t0 = c * 256;
    const int tid = threadIdx.x;
    const int lane = tid & 63, wave = tid >> 6;
    __shared__ __align__(16) float su[256 * Ssz];
    __shared__ __align__(16) float sc[256 * Ssz];
    __shared__ float sp[256 * 17];
    __shared__ float sd[256];

    const float4* ub = (const float4*)(u  + ((size_t)b * Tsz + t0) * Ssz);
    const float4* cb = (const float4*)(Ct + ((size_t)b * Tsz + t0) * Ssz);
#pragma unroll
    for (int i = 0; i < 4; ++i) {
        ((float4*)su)[tid + i * 256] = ub[tid + i * 256];
        ((float4*)sc)[tid + i * 256] = cb[tid + i * 256];
    }
    {
        const float m = rowsum[b * Tsz + t0 + tid] * (1.f / (float)Esz);
        sd[tid] = expf(fminf(fmaxf(-m, -10.f), 10.f));
    }
    __syncthreads();
    if (wave == 0 && lane < 16) {
        float st = 0.f, P = 1.f;
#pragma unroll 8
        for (int i = 0; i < 256; ++i) {
            const float d = sd[i];
            st = st * d + su[i * Ssz + lane];
            sp[i * 17 + lane] = sc[i * Ssz + lane] * st;
            if (lane == 0) { P *= d; sp[i * 17 + 16] = P; }
        }
        send[cid * Ssz + lane] = st;      // chunk-end local state
    }
    __syncthreads();
    float s = 0.f;
#pragma unroll
    for (int j = 0; j < 16; ++j) s += sp[tid * 17 + j];
    ysl[b * Tsz + t0 + tid] = s;
    pt [b * Tsz + t0 + tid] = sp[tid * 17 + 16];
}

__global__ void scanB(const float* __restrict__ send, const float* __restrict__ pt,
                      float* __restrict__ sstart) {
    const int tid = threadIdx.x;          // 64 threads: b = tid>>4, j = tid&15
    if (tid >= 64) return;
    const int b = tid >> 4, j = tid & 15;
    float s = 0.f;
    for (int c = 0; c < 8; ++c) {
        const int cid = b * 8 + c;
        sstart[cid * Ssz + j] = s;
        const float Pc = pt[b * Tsz + c * 256 + 255];
        s = send[cid * Ssz + j] + Pc * s;
    }
}

__global__ void scanC(const float* __restrict__ ysl, const float* __restrict__ pt,
                      const float* __restrict__ sstart, const float* __restrict__ Ct,
                      float* __restrict__ ys) {
    const int cid = blockIdx.x;
    const int b = cid >> 3, c = cid & 7;
    const int t0 = c * 256;
    const int tid = threadIdx.x;
    __shared__ float s0[Ssz];
    if (tid < 16) s0[tid] = sstart[cid * Ssz + tid];
    __syncthreads();
    const int g = b * Tsz + t0 + tid;
    const float4* cr = (const float4*)(Ct + (size_t)g * Ssz);
    float dot = 0.f;
#pragma unroll
    for (int i = 0; i < 4; ++i) {
        float4 v = cr[i];
        dot += v.x * s0[i * 4 + 0] + v.y * s0[i * 4 + 1]
             + v.z * s0[i * 4 + 2] + v.w * s0[i * 4 + 3];
    }
    ys[g] = ysl[g] + pt[g] * dot;
}

// ---------------------------------------------------------------------------
extern "C" void kernel_launch(void* const* d_in, const int* in_sizes, int n_in,
                              void* d_out, int out_size, void* d_ws, size_t ws_size,
                              hipStream_t stream) {
    const float* x      = (const float*)d_in[0];
    const float* in_w   = (const float*)d_in[1];
    const float* in_b   = (const float*)d_in[2];
    const float* conv_w = (const float*)d_in[3];
    const float* conv_b = (const float*)d_in[4];
    const float* dt_w   = (const float*)d_in[5];
    const float* dt_b   = (const float*)d_in[6];
    const float* B_w    = (const float*)d_in[7];
    const float* B_b    = (const float*)d_in[8];
    const float* C_w    = (const float*)d_in[9];
    const float* C_b    = (const float*)d_in[10];
    const float* D_w    = (const float*)d_in[11];
    const float* D_b    = (const float*)d_in[12];
    const float* out_w  = (const float*)d_in[13];
    const float* out_b  = (const float*)d_in[14];
    float* out = (float*)d_out;

    char* ws = (char*)d_ws;
    auto alloc = [&](size_t bytes) {
        char* p = ws;
        ws += (bytes + 255) & ~(size_t)255;
        return p;
    };
    unsigned char* x_f8    = (unsigned char*)alloc((size_t)Mrows * Dsz);          //  8 MB
    unsigned char* inw_f8  = (unsigned char*)alloc((size_t)2 * Esz * Dsz);        //  4 MB
    unsigned char* dtw_f8  = (unsigned char*)alloc((size_t)Esz * Esz);            //  4 MB
    unsigned char* outw_f8 = (unsigned char*)alloc((size_t)Dsz * Esz);            //  2 MB
    __hip_bfloat16* xp_bf  = (__hip_bfloat16*)alloc((size_t)Mrows * 2 * Esz * 2); // 64 MB
    __hip_bfloat16* xc_bf  = (__hip_bfloat16*)alloc((size_t)Mrows * Esz * 2);     // 32 MB
    unsigned char* xc_f8   = (unsigned char*)alloc((size_t)Mrows * Esz);          // 16 MB
    unsigned char* s_f8    = (unsigned char*)alloc((size_t)Mrows * Esz);          // 16 MB
    __hip_bfloat16* wb_bf  = (__hip_bfloat16*)alloc((size_t)48 * Esz * 2);
    float* rowsum = (float*)alloc(Mrows * 4);
    float* u_buf  = (float*)alloc((size_t)Mrows * Ssz * 4);
    float* ct_buf = (float*)alloc((size_t)Mrows * Ssz * 4);
    float* ys_buf = (float*)alloc(Mrows * 4);
    float* ysl_buf = (float*)alloc(Mrows * 4);
    float* pt_buf  = (float*)alloc(Mrows * 4);
    float* send_buf = (float*)alloc(32 * Ssz * 4);
    float* sstart_buf = (float*)alloc(32 * Ssz * 4);
    (void)alloc(65536);            // pad: fp8 tail over-reads stay inside ws

    hipMemsetAsync(rowsum, 0, Mrows * 4, stream);

    cvt_all<<<4608, 256, 0, stream>>>((const float4*)x, (const float4*)in_w,
                                      (const float4*)dt_w, (const float4*)out_w,
                                      (int*)x_f8, (int*)inw_f8, (int*)dtw_f8,
                                      (int*)outw_f8);
    pack_bcd<<<48 * Esz / 256, 256, 0, stream>>>(B_w, C_w, D_w, wb_bf);

    // GEMM1 (MX-fp8 128x128): xp = x @ in_w^T + in_b  (8192x4096x1024) -> bf16
    gemm_f8<0, 127, 121><<<dim3(4096 / 128, Mrows / 128), 256, 0, stream>>>(
        x_f8, inw_f8, in_b, Mrows, 4096, 1024, xp_bf, nullptr, nullptr, nullptr, nullptr);

    // fused conv+SiLU (-> xc bf16, xc*16 fp8) + gate SiLU (-> S*16 fp8)
    conv_gate_k<<<(Mrows * Esz / 8) / 256, 256, 0, stream>>>(
        xp_bf, conv_w, conv_b, xc_bf, (int2*)xc_f8, (int2*)s_f8);

    // GEMM2 (MX-fp8): softplus(xc @ dt_w^T + dt_b) row-sums (8192x2048x2048)
    gemm_f8<1, 123, 121><<<dim3(Esz / 128, Mrows / 128), 256, 0, stream>>>(
        xc_f8, dtw_f8, dt_b, Mrows, Esz, Esz, nullptr, rowsum, nullptr, nullptr, nullptr);

    // B/C/D projections + u = Bt*Dt (bf16 xc), 256-block low-sync version
    bcd_mfma2<<<Mrows / 32, 128, 0, stream>>>(xc_bf, wb_bf, B_b, C_b, D_b, u_buf, ct_buf);

    // segmented scan -> ys
    scanA<<<32, 256, 0, stream>>>(rowsum, u_buf, ct_buf, ysl_buf, pt_buf, send_buf);
    scanB<<<1, 64, 0, stream>>>(send_buf, pt_buf, sstart_buf);
    scanC<<<32, 256, 0, stream>>>(ysl_buf, pt_buf, sstart_buf, ct_buf, ys_buf);

    // GEMM3 (MX-fp8): out = x + ys[row]*(S @ out_w^T) + out_b (8192x1024x2048)
    gemm_f8<2, 123, 121><<<dim3(Dsz / 128, Mrows / 128), 256, 0, stream>>>(
        s_f8, outw_f8, out_b, Mrows, Dsz, Esz, nullptr, nullptr, x, ys_buf, out);
}

// Round 8
// 380.624 us; speedup vs baseline: 1.3441x; 1.0135x over previous
//
#include <hip/hip_runtime.h>
#include <hip/hip_bf16.h>

// Problem constants
#define Bsz 4
#define Tsz 2048
#define Dsz 1024
#define Ssz 16
#define Esz 2048
#define Mrows (Bsz*Tsz)        // 8192

typedef __attribute__((ext_vector_type(8))) short short8;
typedef __attribute__((ext_vector_type(4))) float floatx4;
typedef __attribute__((ext_vector_type(8))) int int8v;
typedef __attribute__((ext_vector_type(4))) int int4v;
typedef __attribute__((ext_vector_type(4))) unsigned short ushort4v;

__device__ __forceinline__ void async_ld16(const void* g, void* l) {
    __builtin_amdgcn_global_load_lds(
        (const __attribute__((address_space(1))) void*)g,
        (__attribute__((address_space(3))) void*)l,
        16, 0, 0);
}

__device__ __forceinline__ float sigmoidf_(float v) { return 1.f / (1.f + expf(-v)); }
__device__ __forceinline__ float bf2f(unsigned short u) {
    union { unsigned u32; float f; } c; c.u32 = (unsigned)u << 16; return c.f;
}
__device__ __forceinline__ unsigned short f2bf(float f) {
    __hip_bfloat16 h = __float2bfloat16(f);
    return *(unsigned short*)&h;
}
__device__ __forceinline__ int pk_fp8x4(float a, float b, float c, float d) {
    int lo = __builtin_amdgcn_cvt_pk_fp8_f32(a, b, 0, 0);
    int hi = __builtin_amdgcn_cvt_pk_fp8_f32(c, d, 0, 0);
    return (lo & 0xFFFF) | (hi << 16);
}

// s_waitcnt immediates (gfx9): vm[3:0]|exp[6:4]|lgkm[11:8]|vm[15:14]
#define WAIT_VM(N)   (0xF70 | (N))
#define WAIT_LGKM(N) (0xC07F | ((N) << 8))

// ---------------------------------------------------------------------------
// merged conversions: x -> fp8 (x1), in_w/dt_w/out_w -> fp8 (x64), and
// B/C/D pack -> Wb bf16 (R8: absorbed pack_bcd, one fewer launch).
// ---------------------------------------------------------------------------
#define CV_S0 2097152   // x:     8388608 f32 / 4
#define CV_S1 3145728   // in_w: +4194304 / 4
#define CV_S2 4194304   // dt_w: +4194304 / 4
#define CV_S3 4718592   // out_w:+2097152 / 4
#define CV_S4 4743168   // bcd:  +98304 / 4 (3 x 16 x 2048)
__global__ void cvt_all(const float4* __restrict__ x,  const float4* __restrict__ iw,
                        const float4* __restrict__ dw, const float4* __restrict__ ow,
                        const float4* __restrict__ Bw, const float4* __restrict__ Cw,
                        const float4* __restrict__ Dw,
                        int* __restrict__ x8, int* __restrict__ iw8,
                        int* __restrict__ dw8, int* __restrict__ ow8,
                        ushort4v* __restrict__ wb) {
    int i = blockIdx.x * blockDim.x + threadIdx.x;
    const int stride = gridDim.x * blockDim.x;
    for (; i < CV_S4; i += stride) {
        if (i < CV_S0) {
            float4 v = x[i];
            x8[i] = pk_fp8x4(v.x, v.y, v.z, v.w);
        } else if (i < CV_S1) {
            const int j = i - CV_S0;
            float4 v = iw[j];
            iw8[j] = pk_fp8x4(v.x * 64.f, v.y * 64.f, v.z * 64.f, v.w * 64.f);
        } else if (i < CV_S2) {
            const int j = i - CV_S1;
            float4 v = dw[j];
            dw8[j] = pk_fp8x4(v.x * 64.f, v.y * 64.f, v.z * 64.f, v.w * 64.f);
        } else if (i < CV_S3) {
            const int j = i - CV_S2;
            float4 v = ow[j];
            ow8[j] = pk_fp8x4(v.x * 64.f, v.y * 64.f, v.z * 64.f, v.w * 64.f);
        } else {
            const int j = i - CV_S3;        // 0..24575: 8192 B, 8192 C, 8192 D
            float4 v;
            if (j < 8192)       v = Bw[j];
            else if (j < 16384) v = Cw[j - 8192];
            else                v = Dw[j - 16384];
            ushort4v o;
            o[0] = f2bf(v.x); o[1] = f2bf(v.y); o[2] = f2bf(v.z); o[3] = f2bf(v.w);
            wb[j] = o;
        }
    }
}

// ---------------------------------------------------------------------------
// MX-fp8 GEMM (R1-proven hot loop, untouched).  128x128 tile, BK=128B,
// 4 waves 2x2, per-wave 64x64 via 4x4 mfma_scale_f32_16x16x128_f8f6f4;
// 2-stage LDS, dist-2 DMA prefetch, vmcnt(8) in-loop, mod-8 XOR swizzle.
// MODE: 0 bf16 store, 1 softplus rowsum, 2 fp32 resid + ys[row]*acc,
//       3 split: nt<16 -> bf16 xp_main [row][2048]; nt>=16 -> SiLU+fp8*16
//         gate8 [row][2048]  (R8: kills gate-half bf16 write + re-read).
// ---------------------------------------------------------------------------
template<int MODE, int SA, int SB>
__launch_bounds__(256, 2)
__global__ void gemm_f8(const unsigned char* __restrict__ A,
                        const unsigned char* __restrict__ Bw,
                        const float* __restrict__ bias,
                        int M, int N, int K,
                        __hip_bfloat16* __restrict__ outb,
                        float* __restrict__ rowsum,
                        const float* __restrict__ resid,
                        const float* __restrict__ ysv,
                        float* __restrict__ outf,
                        unsigned char* __restrict__ gate8) {
    __shared__ __align__(16) unsigned char sA[2 * 16384];  // 128 rows x 128B
    __shared__ __align__(16) unsigned char sB[2 * 16384];

    const int tid  = threadIdx.x;
    const int wave = tid >> 6, lane = tid & 63;
    const int wm = wave >> 1, wn = wave & 1;
    const int q = lane >> 4, lr = lane & 15;

    // XCD-aware remap: each XCD owns a contiguous M-stripe.
    const int gx = gridDim.x, gy = gridDim.y;
    const int flat = blockIdx.y * gx + blockIdx.x;
    const int stripe = gy >> 3;
    const int xcd = flat & 7, local = flat >> 3;
    const int mt = xcd * stripe + (local % stripe);
    const int nt = local / stripe;
    const int m0 = mt * 128, n0 = nt * 128;

    floatx4 acc[4][4];
#pragma unroll
    for (int i = 0; i < 4; ++i)
#pragma unroll
        for (int j = 0; j < 4; ++j) acc[i][j] = (floatx4){0.f, 0.f, 0.f, 0.f};

    const unsigned char* pa[4];
    const unsigned char* pb[4];
#pragma unroll
    for (int i = 0; i < 4; ++i) {
        const int idx = i * 256 + tid, row = idx >> 3, s = idx & 7;
        pa[i] = A + (size_t)(m0 + row) * K + ((s ^ (row & 7)) * 16);
        pb[i] = Bw + (size_t)(n0 + row) * K + ((s ^ (row & 7)) * 16);
    }

    const int rA = wm * 64 + lr, rB = wn * 64 + lr;
    const int oA0 = rA * 128 + (((2 * q)     ^ (rA & 7)) * 16);
    const int oA1 = rA * 128 + (((2 * q + 1) ^ (rA & 7)) * 16);
    const int oB0 = rB * 128 + (((2 * q)     ^ (rB & 7)) * 16);
    const int oB1 = rB * 128 + (((2 * q + 1) ^ (rB & 7)) * 16);

#define F8_ISSUE(ST) do {                                                      \
        _Pragma("unroll")                                                      \
        for (int i = 0; i < 4; ++i) {                                          \
            async_ld16(pa[i], &sA[(ST) * 16384 + (i * 256 + wave * 64) * 16]); \
            pa[i] += 128;                                                      \
        }                                                                      \
        _Pragma("unroll")                                                      \
        for (int i = 0; i < 4; ++i) {                                          \
            async_ld16(pb[i], &sB[(ST) * 16384 + (i * 256 + wave * 64) * 16]); \
            pb[i] += 128;                                                      \
        }                                                                      \
    } while (0)

#define F8_STEP(ST) do {                                                       \
        asm volatile("" ::: "memory");                                         \
        __builtin_amdgcn_s_waitcnt(WAIT_VM(8));   /* this tile landed */       \
        __builtin_amdgcn_s_barrier();                                          \
        asm volatile("" ::: "memory");                                         \
        int8v a8[4], b8[4];                                                    \
        _Pragma("unroll")                                                      \
        for (int i = 0; i < 4; ++i) {                                          \
            int4v lo = *(const int4v*)&sA[(ST) * 16384 + oA0 + i * 2048];      \
            int4v hi = *(const int4v*)&sA[(ST) * 16384 + oA1 + i * 2048];      \
            a8[i] = __builtin_shufflevector(lo, hi, 0, 1, 2, 3, 4, 5, 6, 7);   \
        }                                                                      \
        _Pragma("unroll")                                                      \
        for (int j = 0; j < 4; ++j) {                                          \
            int4v lo = *(const int4v*)&sB[(ST) * 16384 + oB0 + j * 2048];      \
            int4v hi = *(const int4v*)&sB[(ST) * 16384 + oB1 + j * 2048];      \
            b8[j] = __builtin_shufflevector(lo, hi, 0, 1, 2, 3, 4, 5, 6, 7);   \
        }                                                                      \
        asm volatile("" ::: "memory");                                         \
        __builtin_amdgcn_s_waitcnt(WAIT_LGKM(0)); /* frags landed */           \
        __builtin_amdgcn_s_barrier();             /* stage reusable */         \
        asm volatile("" ::: "memory");                                         \
        F8_ISSUE(ST);                             /* tile kt+2 -> stage ST */  \
        _Pragma("unroll")                                                      \
        for (int i = 0; i < 4; ++i)                                            \
            _Pragma("unroll")                                                  \
            for (int j = 0; j < 4; ++j)                                        \
                acc[i][j] = __builtin_amdgcn_mfma_scale_f32_16x16x128_f8f6f4(  \
                    a8[i], b8[j], acc[i][j], 0, 0, 0, SA, 0, SB);              \
    } while (0)

    const int nit = K >> 8;        // (K/128)/2 double-steps; K mult of 256
    F8_ISSUE(0);
    F8_ISSUE(1);
    for (int it = 0; it < nit; ++it) {
        F8_STEP(0);
        F8_STEP(1);
    }
#undef F8_STEP
#undef F8_ISSUE
    asm volatile("" ::: "memory");
    __builtin_amdgcn_s_waitcnt(WAIT_VM(0));       // drain 2 garbage tail tiles

    // epilogue: C/D layout col = lane&15, row = (lane>>4)*4 + reg
    if (MODE == 0) {
#pragma unroll
        for (int i = 0; i < 4; ++i) {
            const int row = m0 + wm * 64 + i * 16 + q * 4;
#pragma unroll
            for (int j = 0; j < 4; ++j) {
                const int col = n0 + wn * 64 + j * 16 + lr;
                const float bc = bias[col];
#pragma unroll
                for (int r = 0; r < 4; ++r)
                    outb[(size_t)(row + r) * N + col] = __float2bfloat16(acc[i][j][r] + bc);
            }
        }
    } else if (MODE == 1) {
#pragma unroll
        for (int i = 0; i < 4; ++i) {
            float rs[4] = {0.f, 0.f, 0.f, 0.f};
#pragma unroll
            for (int j = 0; j < 4; ++j) {
                const int col = n0 + wn * 64 + j * 16 + lr;
                const float bc = bias[col];
#pragma unroll
                for (int r = 0; r < 4; ++r) {
                    float v = acc[i][j][r] + bc;
                    float sp = (v > 20.f) ? v : log1pf(expf(v));
                    rs[r] += sp;
                }
            }
#pragma unroll
            for (int r = 0; r < 4; ++r) {
                float v = rs[r];
                v += __shfl_xor(v, 1); v += __shfl_xor(v, 2);
                v += __shfl_xor(v, 4); v += __shfl_xor(v, 8);
                if (lr == 0)
                    atomicAdd(&rowsum[m0 + wm * 64 + i * 16 + q * 4 + r], v);
            }
        }
    } else if (MODE == 2) {
#pragma unroll
        for (int i = 0; i < 4; ++i) {
            const int row = m0 + wm * 64 + i * 16 + q * 4;
#pragma unroll
            for (int j = 0; j < 4; ++j) {
                const int col = n0 + wn * 64 + j * 16 + lr;
                const float bc = bias[col];
#pragma unroll
                for (int r = 0; r < 4; ++r) {
                    const size_t idx = (size_t)(row + r) * N + col;
                    outf[idx] = resid[idx] + ysv[row + r] * acc[i][j][r] + bc;
                }
            }
        }
    } else {
        // MODE 3: GEMM1 split.  main (nt<16): bf16, stride 2048.
        //         gate (nt>=16): SiLU then fp8 x16, stride 2048.
        if (nt < 16) {
#pragma unroll
            for (int i = 0; i < 4; ++i) {
                const int row = m0 + wm * 64 + i * 16 + q * 4;
#pragma unroll
                for (int j = 0; j < 4; ++j) {
                    const int col = n0 + wn * 64 + j * 16 + lr;
                    const float bc = bias[col];
#pragma unroll
                    for (int r = 0; r < 4; ++r)
                        outb[(size_t)(row + r) * Esz + col] =
                            __float2bfloat16(acc[i][j][r] + bc);
                }
            }
        } else {
#pragma unroll
            for (int i = 0; i < 4; ++i) {
                const int row = m0 + wm * 64 + i * 16 + q * 4;
#pragma unroll
                for (int j = 0; j < 4; ++j) {
                    const int col = n0 + wn * 64 + j * 16 + lr;
                    const float bc = bias[col];
                    const int colg = col - Esz;
#pragma unroll
                    for (int r = 0; r < 4; ++r) {
                        const float v = acc[i][j][r] + bc;
                        const float sil = v * sigmoidf_(v) * 16.f;
                        const int pk = __builtin_amdgcn_cvt_pk_fp8_f32(sil, sil, 0, 0);
                        gate8[(size_t)(row + r) * Esz + colg] = (unsigned char)(pk & 0xFF);
                    }
                }
            }
        }
    }
}

// ---------------------------------------------------------------------------
// fused conv pass over xp_main (stride 2048): depthwise conv(k=3)+bias+SiLU
// -> xc (bf16, for bcd) + xc*16 (fp8, GEMM2 A).  Gate handled in GEMM1.
// ---------------------------------------------------------------------------
__global__ void conv_gate_k(const __hip_bfloat16* __restrict__ xpm,
                            const float* __restrict__ cw,
                            const float* __restrict__ cb,
                            __hip_bfloat16* __restrict__ xc,
                            int2* __restrict__ xc8) {
    const int idx8 = blockIdx.x * blockDim.x + threadIdx.x;
    const int e = (idx8 & (Esz / 8 - 1)) * 8;
    const int r = idx8 >> 8;
    const int t = r & (Tsz - 1);
    const unsigned short* row0 = (const unsigned short*)(xpm + (size_t)r * Esz + e);
    short8 vm1 = (t > 0)       ? *(const short8*)(row0 - Esz) : (short8){0,0,0,0,0,0,0,0};
    short8 v00 = *(const short8*)row0;
    short8 vp1 = (t < Tsz - 1) ? *(const short8*)(row0 + Esz) : (short8){0,0,0,0,0,0,0,0};
    short8 o;
    float sil[8];
#pragma unroll
    for (int k = 0; k < 8; ++k) {
        const int ek = e + k;
        float v = bf2f((unsigned short)vm1[k]) * cw[ek * 3 + 0]
                + bf2f((unsigned short)v00[k]) * cw[ek * 3 + 1]
                + bf2f((unsigned short)vp1[k]) * cw[ek * 3 + 2] + cb[ek];
        sil[k] = v * sigmoidf_(v);
        o[k] = (short)f2bf(sil[k]);
    }
    *(short8*)(xc + (size_t)idx8 * 8) = o;
    int2 p;
    p.x = pk_fp8x4(sil[0] * 16.f, sil[1] * 16.f, sil[2] * 16.f, sil[3] * 16.f);
    p.y = pk_fp8x4(sil[4] * 16.f, sil[5] * 16.f, sil[6] * 16.f, sil[7] * 16.f);
    xc8[idx8] = p;
}

// ---------------------------------------------------------------------------
// bcd (R7-proven): xc[M,E] @ Wb[48,E]^T, 256 blocks x 2 waves, 32 rows/block.
// Wb chunk staged once per 256-K; A read directly from global.
// ---------------------------------------------------------------------------
__launch_bounds__(128)
__global__ void bcd_mfma2(const __hip_bfloat16* __restrict__ xc,
                          const __hip_bfloat16* __restrict__ Wb,
                          const float* __restrict__ Bb, const float* __restrict__ Cb,
                          const float* __restrict__ Db,
                          float* __restrict__ u, float* __restrict__ Ct) {
    __shared__ __align__(16) __hip_bfloat16 sW[48 * 256];   // 24576 B
    const int tid = threadIdx.x;
    const int wave = tid >> 6, lane = tid & 63;
    const int q = lane >> 4, lr = lane & 15;
    const int m0 = blockIdx.x * 32;

    floatx4 acc[3];
#pragma unroll
    for (int j = 0; j < 3; ++j) acc[j] = (floatx4){0.f, 0.f, 0.f, 0.f};

    const __hip_bfloat16* arow = xc + (size_t)(m0 + wave * 16 + lr) * Esz;

    for (int kt = 0; kt < 8; ++kt) {
        const int k0 = kt << 8;
        __syncthreads();                          // prev chunk reads done
#pragma unroll
        for (int j = 0; j < 12; ++j) {
            const int idx = j * 128 + tid;
            const int row = idx >> 5, ch = idx & 31;
            async_ld16(&Wb[(size_t)row * Esz + k0 + ch * 8],
                       (__hip_bfloat16*)sW + idx * 8);
        }
        __builtin_amdgcn_s_waitcnt(WAIT_VM(0));
        __syncthreads();                          // chunk visible to all

        short8 af[8];
#pragma unroll
        for (int ks = 0; ks < 8; ++ks)
            af[ks] = *(const short8*)&arow[k0 + ks * 32 + q * 8];
#pragma unroll
        for (int ks = 0; ks < 8; ++ks) {
#pragma unroll
            for (int j = 0; j < 3; ++j) {
                short8 wf = *(const short8*)&sW[(j * 16 + lr) * 256 + ks * 32 + q * 8];
                acc[j] = __builtin_amdgcn_mfma_f32_16x16x32_bf16(af[ks], wf, acc[j], 0, 0, 0);
            }
        }
    }

    const int row = m0 + wave * 16 + q * 4;
    const float bb = Bb[lr], cbv = Cb[lr], db = Db[lr];
#pragma unroll
    for (int r = 0; r < 4; ++r) {
        const float bt = acc[0][r] + bb;
        const float ct = acc[1][r] + cbv;
        const float dt = acc[2][r] + db;
        u [(size_t)(row + r) * Ssz + lr] = bt * dt;
        Ct[(size_t)(row + r) * Ssz + lr] = ct;
    }
}

// ---------------------------------------------------------------------------
// Segmented scan (R7-proven math).  decay scalar per t =>
// ys_t = ysl_t + P_t*(C_t.S0).  R8: scanB folded into scanC (each chunk
// chains its own <=7-step prefix from send/pt; redundant but trivial).
// ---------------------------------------------------------------------------
__global__ void scanA(const float* __restrict__ rowsum, const float* __restrict__ u,
                      const float* __restrict__ Ct,
                      float* __restrict__ ysl, float* __restrict__ pt,
                      float* __restrict__ send) {
    const int cid = blockIdx.x;           // 0..31
    const int b = cid >> 3, c = cid & 7;
    const int t0 = c * 256;
    const int tid = threadIdx.x;
    const int lane = tid & 63, wave = tid >> 6;
    __shared__ __align__(16) float su[256 * Ssz];
    __shared__ __align__(16) float sc[256 * Ssz];
    __shared__ float sp[256 * 17];
    __shared__ float sd[256];

    const float4* ub = (const float4*)(u  + ((size_t)b * Tsz + t0) * Ssz);
    const float4* cb = (const float4*)(Ct + ((size_t)b * Tsz + t0) * Ssz);
#pragma unroll
    for (int i = 0; i < 4; ++i) {
        ((float4*)su)[tid + i * 256] = ub[tid + i * 256];
        ((float4*)sc)[tid + i * 256] = cb[tid + i * 256];
    }
    {
        const float m = rowsum[b * Tsz + t0 + tid] * (1.f / (float)Esz);
        sd[tid] = expf(fminf(fmaxf(-m, -10.f), 10.f));
    }
    __syncthreads();
    if (wave == 0 && lane < 16) {
        float st = 0.f, P = 1.f;
#pragma unroll 8
        for (int i = 0; i < 256; ++i) {
            const float d = sd[i];
            st = st * d + su[i * Ssz + lane];
            sp[i * 17 + lane] = sc[i * Ssz + lane] * st;
            if (lane == 0) { P *= d; sp[i * 17 + 16] = P; }
        }
        send[cid * Ssz + lane] = st;      // chunk-end local state
    }
    __syncthreads();
    float s = 0.f;
#pragma unroll
    for (int j = 0; j < 16; ++j) s += sp[tid * 17 + j];
    ysl[b * Tsz + t0 + tid] = s;
    pt [b * Tsz + t0 + tid] = sp[tid * 17 + 16];
}

__global__ void scanC(const float* __restrict__ ysl, const float* __restrict__ pt,
                      const float* __restrict__ send, const float* __restrict__ Ct,
                      float* __restrict__ ys) {
    const int cid = blockIdx.x;
    const int b = cid >> 3, c = cid & 7;
    const int t0 = c * 256;
    const int tid = threadIdx.x;
    __shared__ float s0[Ssz];
    if (tid < 16) {
        float s = 0.f;
        for (int cc = 0; cc < c; ++cc) {
            const float Pc = pt[(b * 8 + cc) * 256 + 255];
            s = send[(b * 8 + cc) * Ssz + tid] + Pc * s;
        }
        s0[tid] = s;
    }
    __syncthreads();
    const int g = b * Tsz + t0 + tid;
    const float4* cr = (const float4*)(Ct + (size_t)g * Ssz);
    float dot = 0.f;
#pragma unroll
    for (int i = 0; i < 4; ++i) {
        float4 v = cr[i];
        dot += v.x * s0[i * 4 + 0] + v.y * s0[i * 4 + 1]
             + v.z * s0[i * 4 + 2] + v.w * s0[i * 4 + 3];
    }
    ys[g] = ysl[g] + pt[g] * dot;
}

// ---------------------------------------------------------------------------
extern "C" void kernel_launch(void* const* d_in, const int* in_sizes, int n_in,
                              void* d_out, int out_size, void* d_ws, size_t ws_size,
                              hipStream_t stream) {
    const float* x      = (const float*)d_in[0];
    const float* in_w   = (const float*)d_in[1];
    const float* in_b   = (const float*)d_in[2];
    const float* conv_w = (const float*)d_in[3];
    const float* conv_b = (const float*)d_in[4];
    const float* dt_w   = (const float*)d_in[5];
    const float* dt_b   = (const float*)d_in[6];
    const float* B_w    = (const float*)d_in[7];
    const float* B_b    = (const float*)d_in[8];
    const float* C_w    = (const float*)d_in[9];
    const float* C_b    = (const float*)d_in[10];
    const float* D_w    = (const float*)d_in[11];
    const float* D_b    = (const float*)d_in[12];
    const float* out_w  = (const float*)d_in[13];
    const float* out_b  = (const float*)d_in[14];
    float* out = (float*)d_out;

    char* ws = (char*)d_ws;
    auto alloc = [&](size_t bytes) {
        char* p = ws;
        ws += (bytes + 255) & ~(size_t)255;
        return p;
    };
    unsigned char* x_f8    = (unsigned char*)alloc((size_t)Mrows * Dsz);          //  8 MB
    unsigned char* inw_f8  = (unsigned char*)alloc((size_t)2 * Esz * Dsz);        //  4 MB
    unsigned char* dtw_f8  = (unsigned char*)alloc((size_t)Esz * Esz);            //  4 MB
    unsigned char* outw_f8 = (unsigned char*)alloc((size_t)Dsz * Esz);            //  2 MB
    __hip_bfloat16* xpm_bf = (__hip_bfloat16*)alloc((size_t)Mrows * Esz * 2);     // 32 MB (main only)
    __hip_bfloat16* xc_bf  = (__hip_bfloat16*)alloc((size_t)Mrows * Esz * 2);     // 32 MB
    unsigned char* xc_f8   = (unsigned char*)alloc((size_t)Mrows * Esz);          // 16 MB
    unsigned char* s_f8    = (unsigned char*)alloc((size_t)Mrows * Esz);          // 16 MB
    __hip_bfloat16* wb_bf  = (__hip_bfloat16*)alloc((size_t)48 * Esz * 2);
    float* rowsum = (float*)alloc(Mrows * 4);
    float* u_buf  = (float*)alloc((size_t)Mrows * Ssz * 4);
    float* ct_buf = (float*)alloc((size_t)Mrows * Ssz * 4);
    float* ys_buf = (float*)alloc(Mrows * 4);
    float* ysl_buf = (float*)alloc(Mrows * 4);
    float* pt_buf  = (float*)alloc(Mrows * 4);
    float* send_buf = (float*)alloc(32 * Ssz * 4);
    (void)alloc(65536);            // pad: fp8 tail over-reads stay inside ws

    hipMemsetAsync(rowsum, 0, Mrows * 4, stream);

    // conversions (x/in_w/dt_w/out_w -> fp8, B/C/D -> Wb bf16)
    cvt_all<<<4608, 256, 0, stream>>>((const float4*)x, (const float4*)in_w,
                                      (const float4*)dt_w, (const float4*)out_w,
                                      (const float4*)B_w, (const float4*)C_w,
                                      (const float4*)D_w,
                                      (int*)x_f8, (int*)inw_f8, (int*)dtw_f8,
                                      (int*)outw_f8, (ushort4v*)wb_bf);

    // GEMM1 (MX-fp8, MODE3 split): main -> xpm bf16; gate -> SiLU fp8 S*16
    gemm_f8<3, 127, 121><<<dim3(4096 / 128, Mrows / 128), 256, 0, stream>>>(
        x_f8, inw_f8, in_b, Mrows, 4096, 1024, xpm_bf, nullptr, nullptr, nullptr,
        nullptr, s_f8);

    // fused conv+SiLU (-> xc bf16, xc*16 fp8)
    conv_gate_k<<<(Mrows * Esz / 8) / 256, 256, 0, stream>>>(
        xpm_bf, conv_w, conv_b, xc_bf, (int2*)xc_f8);

    // GEMM2 (MX-fp8): softplus(xc @ dt_w^T + dt_b) row-sums (8192x2048x2048)
    gemm_f8<1, 123, 121><<<dim3(Esz / 128, Mrows / 128), 256, 0, stream>>>(
        xc_f8, dtw_f8, dt_b, Mrows, Esz, Esz, nullptr, rowsum, nullptr, nullptr,
        nullptr, nullptr);

    // B/C/D projections + u = Bt*Dt (bf16 xc)
    bcd_mfma2<<<Mrows / 32, 128, 0, stream>>>(xc_bf, wb_bf, B_b, C_b, D_b, u_buf, ct_buf);

    // segmented scan -> ys (scanB folded into scanC)
    scanA<<<32, 256, 0, stream>>>(rowsum, u_buf, ct_buf, ysl_buf, pt_buf, send_buf);
    scanC<<<32, 256, 0, stream>>>(ysl_buf, pt_buf, send_buf, ct_buf, ys_buf);

    // GEMM3 (MX-fp8): out = x + ys[row]*(S @ out_w^T) + out_b (8192x1024x2048)
    gemm_f8<2, 123, 121><<<dim3(Dsz / 128, Mrows / 128), 256, 0, stream>>>(
        s_f8, outw_f8, out_b, Mrows, Dsz, Esz, nullptr, nullptr, x, ys_buf, out,
        nullptr);
}